// Round 1
// baseline (497.837 us; speedup 1.0000x reference)
//
#include <hip/hip_runtime.h>
#include <math.h>

// Problem constants
#define NPOOL 110592          // 48^3 elements per channel after pooling
#define NVAL  97336           // 46^3 valid window positions
#define NCH   8               // N*C = 2*4 channels

// Pair tables: unordered 2D-offset pairs (P <= Q), P,Q in [0,9)
__device__ const unsigned char c_pairP[45] = {
  0,0,0,0,0,0,0,0,0, 1,1,1,1,1,1,1,1, 2,2,2,2,2,2,2,
  3,3,3,3,3,3, 4,4,4,4,4, 5,5,5,5, 6,6,6, 7,7, 8};
__device__ const unsigned char c_pairQ[45] = {
  0,1,2,3,4,5,6,7,8, 1,2,3,4,5,6,7,8, 2,3,4,5,6,7,8,
  3,4,5,6,7,8, 4,5,6,7,8, 5,6,7,8, 6,7,8, 7,8, 8};

// ---------------------------------------------------------------------------
// Kernel 1: fused sigmoid/one-hot + 2x2x2 max-pool.
// One thread per (n, X, Y, Z) pooled voxel, computes all 4 classes.
// ---------------------------------------------------------------------------
__global__ __launch_bounds__(256) void pool_kernel(
    const float* __restrict__ logits, const int* __restrict__ labels,
    float* __restrict__ la_pool, float* __restrict__ pr_pool) {
  int t = blockIdx.x * 256 + threadIdx.x;
  if (t >= 2 * NPOOL) return;
  int Z = t % 48; int tmp = t / 48;
  int Y = tmp % 48; tmp /= 48;
  int X = tmp % 48; int n = tmp / 48;
  int sb = (2 * X) * 9216 + (2 * Y) * 96 + 2 * Z;   // spatial base in 96^3
  int lb = n * 884736 + sb;
  int L0 = labels[lb],        L1 = labels[lb + 1];
  int L2 = labels[lb + 96],   L3 = labels[lb + 97];
  int L4 = labels[lb + 9216], L5 = labels[lb + 9217];
  int L6 = labels[lb + 9312], L7 = labels[lb + 9313];
  int ob = X * 2304 + Y * 48 + Z;
  #pragma unroll
  for (int c = 0; c < 4; c++) {
    const float* lg = logits + (size_t)(n * 4 + c) * 884736 + sb;
    float mx = lg[0];
    mx = fmaxf(mx, lg[1]);    mx = fmaxf(mx, lg[96]);   mx = fmaxf(mx, lg[97]);
    mx = fmaxf(mx, lg[9216]); mx = fmaxf(mx, lg[9217]);
    mx = fmaxf(mx, lg[9312]); mx = fmaxf(mx, lg[9313]);
    // max(sigmoid(x)) == sigmoid(max(x)); probs += 1e-6 (mask is all-true here)
    float pr = 1.0f / (1.0f + expf(-mx)) + 1e-6f;
    float la = (L0 == c || L1 == c || L2 == c || L3 == c ||
                L4 == c || L5 == c || L6 == c || L7 == c) ? 1.0f : 0.0f;
    int oi = (n * 4 + c) * NPOOL + ob;
    la_pool[oi] = la;
    pr_pool[oi] = pr;
  }
}

// ---------------------------------------------------------------------------
// Kernel 2: row sums s[d] = sum over 46^3 window of pool[m + d], per channel.
// One block per (channel, d); 216 blocks.
// ---------------------------------------------------------------------------
__global__ __launch_bounds__(256) void sums_kernel(
    const float* __restrict__ la_pool, const float* __restrict__ pr_pool,
    double* __restrict__ sla, double* __restrict__ spr) {
  int ch = blockIdx.x / 27, d = blockIdx.x % 27;
  int di = d / 9, dj = (d / 3) % 3, dk = d % 3;
  int off = di * 2304 + dj * 48 + dk;
  const float* A = la_pool + ch * NPOOL + off;
  const float* B = pr_pool + ch * NPOOL + off;
  double sa = 0.0, sb = 0.0;
  for (int m = threadIdx.x; m < NVAL; m += 256) {
    int z = m % 46; int t2 = m / 46;
    int y = t2 % 46; int x = t2 / 46;
    int idx = x * 2304 + y * 48 + z;
    sa += (double)A[idx];
    sb += (double)B[idx];
  }
  __shared__ double ra[256], rb[256];
  ra[threadIdx.x] = sa; rb[threadIdx.x] = sb;
  __syncthreads();
  for (int s = 128; s > 0; s >>= 1) {
    if (threadIdx.x < (unsigned)s) {
      ra[threadIdx.x] += ra[threadIdx.x + s];
      rb[threadIdx.x] += rb[threadIdx.x + s];
    }
    __syncthreads();
  }
  if (threadIdx.x == 0) {
    sla[ch * 27 + d] = ra[0];
    spr[ch * 27 + d] = rb[0];
  }
}

// ---------------------------------------------------------------------------
// Kernel 3: Gram matrices (uncentered) via sliding z-window line correlation.
// Block = one (channel, 6x6 xy-tile). Task = (pair of 2D offsets, position).
// Each task computes 9 z-lag accumulators for 4 product types over a z-line.
// ---------------------------------------------------------------------------
#define LSTR 49   // padded z-line stride (odd -> bank decorrelation)
__global__ __launch_bounds__(256) void gram_kernel(
    const float* __restrict__ la_pool, const float* __restrict__ pr_pool,
    double* __restrict__ Gll, double* __restrict__ Gpp, double* __restrict__ Glp) {
  __shared__ float Sla[64 * LSTR];
  __shared__ float Spr[64 * LSTR];
  __shared__ float red[45 * 36];

  int b = blockIdx.x;
  int ch = b >> 6, tile = b & 63;
  int x0 = (tile & 7) * 6, y0 = (tile >> 3) * 6;
  const float* A = la_pool + ch * NPOOL;
  const float* B = pr_pool + ch * NPOOL;

  // Stage 8x8 rows of 48-float z-lines (rows beyond the volume -> 0)
  for (int u = threadIdx.x; u < 64 * 48; u += 256) {
    int r = u / 48, z = u - r * 48;
    int rx = r >> 3, ry = r & 7;
    int gx = x0 + rx, gy = y0 + ry;
    float va = 0.0f, vb = 0.0f;
    if (gx < 48 && gy < 48) {
      int gi = gx * 2304 + gy * 48 + z;
      va = A[gi]; vb = B[gi];
    }
    Sla[r * LSTR + z] = va;
    Spr[r * LSTR + z] = vb;
  }
  for (int u = threadIdx.x; u < 45 * 36; u += 256) red[u] = 0.0f;
  __syncthreads();

  for (int task = threadIdx.x; task < 45 * 36; task += 256) {
    int pair = task % 45;          // lanes spread across pairs (atomic decorrelation)
    int pos = task / 45;           // 0..35
    int px = pos % 6, py = pos / 6;
    if (x0 + px >= 46 || y0 + py >= 46) continue;
    int P = c_pairP[pair], Q = c_pairQ[pair];
    int rowA = ((px + P / 3) * 8 + (py + P % 3)) * LSTR;
    int rowB = ((px + Q / 3) * 8 + (py + Q % 3)) * LSTR;
    const float* laP = Sla + rowA; const float* laQ = Sla + rowB;
    const float* prP = Spr + rowA; const float* prQ = Spr + rowB;

    float aLL[9] = {0}, aPP[9] = {0}, aLPa[9] = {0}, aLPb[9] = {0};
    float a[3], bb[3], p[3], q[3];
    a[0] = laP[0]; a[1] = laP[1];
    bb[0] = laQ[0]; bb[1] = laQ[1];
    p[0] = prP[0]; p[1] = prP[1];
    q[0] = prQ[0]; q[1] = prQ[1];
    #pragma unroll 2
    for (int z = 0; z < 46; z++) {
      a[2] = laP[z + 2]; bb[2] = laQ[z + 2];
      p[2] = prP[z + 2]; q[2]  = prQ[z + 2];
      #pragma unroll
      for (int k1 = 0; k1 < 3; k1++) {
        #pragma unroll
        for (int k2 = 0; k2 < 3; k2++) {
          aLL[k1 * 3 + k2]  += a[k1] * bb[k2];   // la_P x la_Q
          aPP[k1 * 3 + k2]  += p[k1] * q[k2];    // pr_P x pr_Q
          aLPa[k1 * 3 + k2] += a[k1] * q[k2];    // la_P x pr_Q
          aLPb[k1 * 3 + k2] += bb[k1] * p[k2];   // la_Q x pr_P
        }
      }
      a[0] = a[1]; a[1] = a[2];
      bb[0] = bb[1]; bb[1] = bb[2];
      p[0] = p[1]; p[1] = p[2];
      q[0] = q[1]; q[1] = q[2];
    }
    int base = pair * 36;
    #pragma unroll
    for (int k = 0; k < 9; k++) {
      atomicAdd(&red[base + k],      aLL[k]);
      atomicAdd(&red[base + 9 + k],  aPP[k]);
      atomicAdd(&red[base + 18 + k], aLPa[k]);
    }
    if (P != Q) {
      #pragma unroll
      for (int k = 0; k < 9; k++) atomicAdd(&red[base + 27 + k], aLPb[k]);
    }
  }
  __syncthreads();

  // Flush block partials to global fp64 accumulators
  for (int u = threadIdx.x; u < 45 * 36; u += 256) {
    int pair = u / 36, slot = u - pair * 36;
    int P = c_pairP[pair], Q = c_pairQ[pair];
    if (P == Q && slot >= 27) continue;
    float v = red[u];
    int kk = slot % 9, cat = slot / 9;
    int k1 = kk / 3, k2 = kk % 3;
    int d, e; double* dst;
    if (cat == 3) { d = Q * 3 + k1; e = P * 3 + k2; dst = Glp; }
    else {
      d = P * 3 + k1; e = Q * 3 + k2;
      dst = (cat == 0) ? Gll : (cat == 1) ? Gpp : Glp;
    }
    atomicAdd(&dst[ch * 729 + d * 27 + e], (double)v);
  }
}

// ---------------------------------------------------------------------------
// Kernel 4: per-channel 27x27 fp64 linear algebra + final reduction.
// One 64-thread block per channel (8 blocks).
// ---------------------------------------------------------------------------
__device__ void chol27(double* A2, int tid) {
  for (int k = 0; k < 27; k++) {
    if (tid == 0) A2[k * 28] = sqrt(A2[k * 28]);
    __syncthreads();
    if (tid > k && tid < 27) A2[tid * 27 + k] /= A2[k * 28];
    __syncthreads();
    // trailing submatrix rank-1 update (lower triangle), parallel over cells
    for (int u = tid; u < 729; u += 64) {
      int i = u / 27, j = u - i * 27;
      if (i > k && j > k && j <= i)
        A2[u] -= A2[i * 27 + k] * A2[j * 27 + k];
    }
    __syncthreads();
  }
}

__global__ __launch_bounds__(64) void stage2_kernel(
    const double* __restrict__ Gll, const double* __restrict__ Gpp,
    const double* __restrict__ Glp, const double* __restrict__ sla,
    const double* __restrict__ spr, float* __restrict__ out) {
  __shared__ double cLL[729], cPP[729], cLP[729], W[729];
  __shared__ double dred[27];
  int ch = blockIdx.x, tid = threadIdx.x;
  const double Minv = 1.0 / (double)NVAL;
  const double alpha = 5e-4;
  const double* gll = Gll + ch * 729;
  const double* gpp = Gpp + ch * 729;
  const double* glp = Glp + ch * 729;
  const double* sl = sla + ch * 27;
  const double* sp = spr + ch * 27;

  // Center + symmetrize (upper-2D-block cells are authoritative)
  for (int u = tid; u < 729; u += 64) {
    int d = u / 27, e = u - d * 27;
    int Pd = d / 3, Pe = e / 3;
    double vll = (Pd <= Pe) ? gll[d * 27 + e] : gll[e * 27 + d];
    double vpp = (Pd <= Pe) ? gpp[d * 27 + e] : gpp[e * 27 + d];
    cLL[u] = vll - sl[d] * sl[e] * Minv;
    cPP[u] = vpp - sp[d] * sp[e] * Minv + ((d == e) ? alpha : 0.0);
    cLP[u] = glp[u] - sl[d] * sp[e] * Minv;
  }
  __syncthreads();

  // Cholesky of P = pr_cov + alpha*I (in place, lower)
  chol27(cPP, tid);

  // Forward substitution: W = L^{-1} B^T  (thread r owns column r = row r of B)
  if (tid < 27) {
    int r = tid;
    for (int i = 0; i < 27; i++) {
      double s = cLP[r * 27 + i];            // B^T[i][r] = B[r][i]
      for (int j = 0; j < i; j++) s -= cPP[i * 27 + j] * W[j * 27 + r];
      W[i * 27 + r] = s / cPP[i * 28];
    }
  }
  __syncthreads();

  // appro_var + alpha*I = cLL - W^T W + alpha*I  -> reuse cLP
  for (int u = tid; u < 729; u += 64) {
    int i = u / 27, j = u - i * 27;
    double s = 0.0;
    for (int t2 = 0; t2 < 27; t2++) s += W[t2 * 27 + i] * W[t2 * 27 + j];
    cLP[u] = cLL[u] - s + ((i == j) ? alpha : 0.0);
  }
  __syncthreads();

  chol27(cLP, tid);

  if (tid < 27) dred[tid] = log(cLP[tid * 28] + 1e-8);
  __syncthreads();
  if (tid == 0) {
    double s = 0.0;
    for (int i = 0; i < 27; i++) s += dred[i];
    // final = sum over (n,c) of sum_log / (N * HALF_D) = /54
    atomicAdd(out, (float)(s / 54.0));
  }
}

// ---------------------------------------------------------------------------
extern "C" void kernel_launch(void* const* d_in, const int* in_sizes, int n_in,
                              void* d_out, int out_size, void* d_ws, size_t ws_size,
                              hipStream_t stream) {
  const float* logits = (const float*)d_in[0];
  const int* labels = (const int*)d_in[1];
  float* out = (float*)d_out;

  double* Gll = (double*)d_ws;
  double* Gpp = Gll + NCH * 729;
  double* Glp = Gpp + NCH * 729;
  double* sla = Glp + NCH * 729;
  double* spr = sla + NCH * 27;
  float* la_pool = (float*)(spr + NCH * 27);
  float* pr_pool = la_pool + NCH * NPOOL;

  size_t acc_bytes = (size_t)(3 * NCH * 729 + 2 * NCH * 27) * sizeof(double);
  hipMemsetAsync(d_ws, 0, acc_bytes, stream);
  hipMemsetAsync(d_out, 0, sizeof(float), stream);

  pool_kernel<<<(2 * NPOOL + 255) / 256, 256, 0, stream>>>(logits, labels, la_pool, pr_pool);
  sums_kernel<<<NCH * 27, 256, 0, stream>>>(la_pool, pr_pool, sla, spr);
  gram_kernel<<<NCH * 64, 256, 0, stream>>>(la_pool, pr_pool, Gll, Gpp, Glp);
  stage2_kernel<<<NCH, 64, 0, stream>>>(Gll, Gpp, Glp, sla, spr, out);
}

// Round 2
// 454.742 us; speedup vs baseline: 1.0948x; 1.0948x over previous
//
#include <hip/hip_runtime.h>
#include <math.h>

// Problem constants
#define NPOOL 110592          // 48^3 elements per channel after pooling
#define NVAL  97336           // 46^3 valid window positions
#define NCH   8               // N*C = 2*4 channels

typedef float v2f __attribute__((ext_vector_type(2)));

// Pair tables: unordered 2D-offset pairs (P <= Q), P,Q in [0,9)
__device__ const unsigned char c_pairP[45] = {
  0,0,0,0,0,0,0,0,0, 1,1,1,1,1,1,1,1, 2,2,2,2,2,2,2,
  3,3,3,3,3,3, 4,4,4,4,4, 5,5,5,5, 6,6,6, 7,7, 8};
__device__ const unsigned char c_pairQ[45] = {
  0,1,2,3,4,5,6,7,8, 1,2,3,4,5,6,7,8, 2,3,4,5,6,7,8,
  3,4,5,6,7,8, 4,5,6,7,8, 5,6,7,8, 6,7,8, 7,8, 8};
// 4 pair-groups: {0..11},{12..22},{23..33},{34..44}
__device__ const int c_gstart[5] = {0, 12, 23, 34, 45};

// ---------------------------------------------------------------------------
// Kernel 1: fused sigmoid/one-hot + 2x2x2 max-pool. float2/int2 coalesced.
// ---------------------------------------------------------------------------
__global__ __launch_bounds__(256) void pool_kernel(
    const float* __restrict__ logits, const int* __restrict__ labels,
    float* __restrict__ la_pool, float* __restrict__ pr_pool) {
  int t = blockIdx.x * 256 + threadIdx.x;
  if (t >= 2 * NPOOL) return;
  int Z = t % 48; int tmp = t / 48;
  int Y = tmp % 48; tmp /= 48;
  int X = tmp % 48; int n = tmp / 48;
  int sb = (2 * X) * 9216 + (2 * Y) * 96 + 2 * Z;   // spatial base in 96^3
  const int2* lb2 = (const int2*)(labels + n * 884736 + sb);
  int2 La = lb2[0], Lb = lb2[48], Lc = lb2[4608], Ld = lb2[4656];
  int ob = X * 2304 + Y * 48 + Z;
  #pragma unroll
  for (int c = 0; c < 4; c++) {
    const float2* lg2 = (const float2*)(logits + (size_t)(n * 4 + c) * 884736 + sb);
    float2 v0 = lg2[0], v1 = lg2[48], v2 = lg2[4608], v3 = lg2[4656];
    float mx = fmaxf(fmaxf(fmaxf(v0.x, v0.y), fmaxf(v1.x, v1.y)),
                     fmaxf(fmaxf(v2.x, v2.y), fmaxf(v3.x, v3.y)));
    // max(sigmoid(x)) == sigmoid(max(x)); probs += 1e-6 (mask is all-true here)
    float pr = 1.0f / (1.0f + expf(-mx)) + 1e-6f;
    float la = (La.x == c || La.y == c || Lb.x == c || Lb.y == c ||
                Lc.x == c || Lc.y == c || Ld.x == c || Ld.y == c) ? 1.0f : 0.0f;
    int oi = (n * 4 + c) * NPOOL + ob;
    la_pool[oi] = la;
    pr_pool[oi] = pr;
  }
}

// ---------------------------------------------------------------------------
// Kernel 2: row sums s[d] = sum over 46^3 window of pool[m + d], per channel.
// ---------------------------------------------------------------------------
__global__ __launch_bounds__(256) void sums_kernel(
    const float* __restrict__ la_pool, const float* __restrict__ pr_pool,
    double* __restrict__ sla, double* __restrict__ spr) {
  int ch = blockIdx.x / 27, d = blockIdx.x % 27;
  int di = d / 9, dj = (d / 3) % 3, dk = d % 3;
  int off = di * 2304 + dj * 48 + dk;
  const float* A = la_pool + ch * NPOOL + off;
  const float* B = pr_pool + ch * NPOOL + off;
  double sa = 0.0, sb = 0.0;
  for (int m = threadIdx.x; m < NVAL; m += 256) {
    int z = m % 46; int t2 = m / 46;
    int y = t2 % 46; int x = t2 / 46;
    int idx = x * 2304 + y * 48 + z;
    sa += (double)A[idx];
    sb += (double)B[idx];
  }
  __shared__ double ra[256], rb[256];
  ra[threadIdx.x] = sa; rb[threadIdx.x] = sb;
  __syncthreads();
  for (int s = 128; s > 0; s >>= 1) {
    if (threadIdx.x < (unsigned)s) {
      ra[threadIdx.x] += ra[threadIdx.x + s];
      rb[threadIdx.x] += rb[threadIdx.x + s];
    }
    __syncthreads();
  }
  if (threadIdx.x == 0) {
    sla[ch * 27 + d] = ra[0];
    spr[ch * 27 + d] = rb[0];
  }
}

// ---------------------------------------------------------------------------
// Kernel 3: Gram matrices via z-line correlation, float4 LDS reads, packed FMA.
// Block = (channel, 6x6 xy-tile, pair-group of ~11). 2048 blocks.
// ---------------------------------------------------------------------------
#define LSTR 52   // padded z-line stride in floats (13 float4, rows 16B-aligned)

// One window update: 4 product categories, 3 k1-lags, k2 packed {0,1}+scalar 2
#define WIN(A0,A1,A2, B0,B1,B2, P0,P1,P2, Q0,Q1,Q2) do {                 \
    v2f _b01 = {(B0), (B1)};                                             \
    v2f _p01 = {(P0), (P1)};                                             \
    v2f _q01 = {(Q0), (Q1)};                                             \
    const float _as[3] = {(A0), (A1), (A2)};                             \
    const float _bs[3] = {(B0), (B1), (B2)};                             \
    const float _ps[3] = {(P0), (P1), (P2)};                             \
    _Pragma("unroll")                                                    \
    for (int _k = 0; _k < 3; _k++) {                                     \
      v2f _ak = {_as[_k], _as[_k]};                                      \
      LL01[_k]  += _ak * _b01;  LL2[_k]  += _as[_k] * (B2);              \
      LPa01[_k] += _ak * _q01;  LPa2[_k] += _as[_k] * (Q2);              \
      v2f _pk = {_ps[_k], _ps[_k]};                                      \
      PP01[_k]  += _pk * _q01;  PP2[_k]  += _ps[_k] * (Q2);              \
      v2f _bk = {_bs[_k], _bs[_k]};                                      \
      LPb01[_k] += _bk * _p01;  LPb2[_k] += _bs[_k] * (P2);              \
    } } while (0)

__global__ __launch_bounds__(256, 4) void gram_kernel(
    const float* __restrict__ la_pool, const float* __restrict__ pr_pool,
    double* __restrict__ Gll, double* __restrict__ Gpp, double* __restrict__ Glp) {
  __shared__ __align__(16) float Sla[64 * LSTR];
  __shared__ __align__(16) float Spr[64 * LSTR];
  __shared__ float red[12 * 36];

  int b = blockIdx.x;
  int g = b & 3;
  int tile = (b >> 2) & 63;
  int ch = b >> 8;
  int gstart = c_gstart[g];
  int gsize = c_gstart[g + 1] - gstart;
  int x0 = (tile & 7) * 6, y0 = (tile >> 3) * 6;
  const float* A = la_pool + ch * NPOOL;
  const float* B = pr_pool + ch * NPOOL;

  // Stage 8x8 rows of 48-float z-lines as float4 (rows beyond volume -> 0)
  for (int u = threadIdx.x; u < 64 * 12; u += 256) {
    int r = u / 12, zq = u - r * 12;
    int rx = r >> 3, ry = r & 7;
    int gx = x0 + rx, gy = y0 + ry;
    float4 va = {0.f, 0.f, 0.f, 0.f}, vb = va;
    if (gx < 48 && gy < 48) {
      int gi = gx * 2304 + gy * 48;
      va = ((const float4*)(A + gi))[zq];
      vb = ((const float4*)(B + gi))[zq];
    }
    ((float4*)Sla)[r * 13 + zq] = va;
    ((float4*)Spr)[r * 13 + zq] = vb;
  }
  for (int u = threadIdx.x; u < 12 * 36; u += 256) red[u] = 0.0f;
  __syncthreads();

  int ntask = gsize * 36;
  for (int task = threadIdx.x; task < ntask; task += 256) {
    int pairL = task % gsize;      // lanes spread across pairs (atomic decorrelation)
    int pos = task / gsize;        // 0..35
    int px = pos % 6, py = pos / 6;
    if (x0 + px >= 46 || y0 + py >= 46) continue;
    int pair = gstart + pairL;
    int P = c_pairP[pair], Q = c_pairQ[pair];
    int rowA = (px + P / 3) * 8 + (py + P % 3);
    int rowB = (px + Q / 3) * 8 + (py + Q % 3);
    const float4* laP4 = (const float4*)Sla + rowA * 13;
    const float4* laQ4 = (const float4*)Sla + rowB * 13;
    const float4* prP4 = (const float4*)Spr + rowA * 13;
    const float4* prQ4 = (const float4*)Spr + rowB * 13;

    v2f LL01[3] = {}, PP01[3] = {}, LPa01[3] = {}, LPb01[3] = {};
    float LL2[3] = {}, PP2[3] = {}, LPa2[3] = {}, LPb2[3] = {};

    // chunk 0: windows 0,1
    float4 wa = laP4[0], wb = laQ4[0], wp = prP4[0], wq = prQ4[0];
    WIN(wa.x, wa.y, wa.z,  wb.x, wb.y, wb.z,  wp.x, wp.y, wp.z,  wq.x, wq.y, wq.z);
    WIN(wa.y, wa.z, wa.w,  wb.y, wb.z, wb.w,  wp.y, wp.z, wp.w,  wq.y, wq.z, wq.w);
    float a0 = wa.z, a1 = wa.w, b0 = wb.z, b1 = wb.w;
    float p0 = wp.z, p1 = wp.w, q0 = wq.z, q1 = wq.w;
    // chunks 1..11: windows 4j-2 .. 4j+1  (total 2 + 44 = 46 windows)
    #pragma unroll
    for (int j = 1; j <= 11; j++) {
      wa = laP4[j]; wb = laQ4[j]; wp = prP4[j]; wq = prQ4[j];
      WIN(a0, a1, wa.x,      b0, b1, wb.x,      p0, p1, wp.x,      q0, q1, wq.x);
      WIN(a1, wa.x, wa.y,    b1, wb.x, wb.y,    p1, wp.x, wp.y,    q1, wq.x, wq.y);
      WIN(wa.x, wa.y, wa.z,  wb.x, wb.y, wb.z,  wp.x, wp.y, wp.z,  wq.x, wq.y, wq.z);
      WIN(wa.y, wa.z, wa.w,  wb.y, wb.z, wb.w,  wp.y, wp.z, wp.w,  wq.y, wq.z, wq.w);
      a0 = wa.z; a1 = wa.w; b0 = wb.z; b1 = wb.w;
      p0 = wp.z; p1 = wp.w; q0 = wq.z; q1 = wq.w;
    }

    int base = pairL * 36;
    #pragma unroll
    for (int k = 0; k < 3; k++) {
      atomicAdd(&red[base + k * 3 + 0],      LL01[k].x);
      atomicAdd(&red[base + k * 3 + 1],      LL01[k].y);
      atomicAdd(&red[base + k * 3 + 2],      LL2[k]);
      atomicAdd(&red[base + 9 + k * 3 + 0],  PP01[k].x);
      atomicAdd(&red[base + 9 + k * 3 + 1],  PP01[k].y);
      atomicAdd(&red[base + 9 + k * 3 + 2],  PP2[k]);
      atomicAdd(&red[base + 18 + k * 3 + 0], LPa01[k].x);
      atomicAdd(&red[base + 18 + k * 3 + 1], LPa01[k].y);
      atomicAdd(&red[base + 18 + k * 3 + 2], LPa2[k]);
    }
    if (P != Q) {
      #pragma unroll
      for (int k = 0; k < 3; k++) {
        atomicAdd(&red[base + 27 + k * 3 + 0], LPb01[k].x);
        atomicAdd(&red[base + 27 + k * 3 + 1], LPb01[k].y);
        atomicAdd(&red[base + 27 + k * 3 + 2], LPb2[k]);
      }
    }
  }
  __syncthreads();

  // Flush block partials to global fp64 accumulators
  for (int u = threadIdx.x; u < gsize * 36; u += 256) {
    int pairL = u / 36, slot = u - pairL * 36;
    int pair = gstart + pairL;
    int P = c_pairP[pair], Q = c_pairQ[pair];
    if (P == Q && slot >= 27) continue;
    float v = red[u];
    int kk = slot % 9, cat = slot / 9;
    int k1 = kk / 3, k2 = kk % 3;
    int d, e; double* dst;
    if (cat == 3) { d = Q * 3 + k1; e = P * 3 + k2; dst = Glp; }
    else {
      d = P * 3 + k1; e = Q * 3 + k2;
      dst = (cat == 0) ? Gll : (cat == 1) ? Gpp : Glp;
    }
    atomicAdd(&dst[ch * 729 + d * 27 + e], (double)v);
  }
}

// ---------------------------------------------------------------------------
// Kernel 4: per-channel 27x27 fp64 linear algebra + final reduction.
// One 128-thread block per channel (8 blocks).
// ---------------------------------------------------------------------------
__device__ void chol27(double* A2, int tid) {
  for (int k = 0; k < 27; k++) {
    if (tid == 0) A2[k * 28] = sqrt(A2[k * 28]);
    __syncthreads();
    if (tid > k && tid < 27) A2[tid * 27 + k] /= A2[k * 28];
    __syncthreads();
    for (int u = tid; u < 729; u += 128) {
      int i = u / 27, j = u - i * 27;
      if (i > k && j > k && j <= i)
        A2[u] -= A2[i * 27 + k] * A2[j * 27 + k];
    }
    __syncthreads();
  }
}

__global__ __launch_bounds__(128) void stage2_kernel(
    const double* __restrict__ Gll, const double* __restrict__ Gpp,
    const double* __restrict__ Glp, const double* __restrict__ sla,
    const double* __restrict__ spr, float* __restrict__ out) {
  __shared__ double cLL[729], cPP[729], cLP[729], W[729];
  __shared__ double dred[27];
  int ch = blockIdx.x, tid = threadIdx.x;
  const double Minv = 1.0 / (double)NVAL;
  const double alpha = 5e-4;
  const double* gll = Gll + ch * 729;
  const double* gpp = Gpp + ch * 729;
  const double* glp = Glp + ch * 729;
  const double* sl = sla + ch * 27;
  const double* sp = spr + ch * 27;

  // Center + symmetrize (upper-2D-block cells are authoritative)
  for (int u = tid; u < 729; u += 128) {
    int d = u / 27, e = u - d * 27;
    int Pd = d / 3, Pe = e / 3;
    double vll = (Pd <= Pe) ? gll[d * 27 + e] : gll[e * 27 + d];
    double vpp = (Pd <= Pe) ? gpp[d * 27 + e] : gpp[e * 27 + d];
    cLL[u] = vll - sl[d] * sl[e] * Minv;
    cPP[u] = vpp - sp[d] * sp[e] * Minv + ((d == e) ? alpha : 0.0);
    cLP[u] = glp[u] - sl[d] * sp[e] * Minv;
  }
  __syncthreads();

  // Cholesky of P = pr_cov + alpha*I (in place, lower)
  chol27(cPP, tid);

  // Forward substitution: W = L^{-1} B^T  (thread r owns column r = row r of B)
  if (tid < 27) {
    int r = tid;
    for (int i = 0; i < 27; i++) {
      double s = cLP[r * 27 + i];            // B^T[i][r] = B[r][i]
      for (int j = 0; j < i; j++) s -= cPP[i * 27 + j] * W[j * 27 + r];
      W[i * 27 + r] = s / cPP[i * 28];
    }
  }
  __syncthreads();

  // appro_var + alpha*I = cLL - W^T W + alpha*I  -> reuse cLP
  for (int u = tid; u < 729; u += 128) {
    int i = u / 27, j = u - i * 27;
    double s = 0.0;
    for (int t2 = 0; t2 < 27; t2++) s += W[t2 * 27 + i] * W[t2 * 27 + j];
    cLP[u] = cLL[u] - s + ((i == j) ? alpha : 0.0);
  }
  __syncthreads();

  chol27(cLP, tid);

  if (tid < 27) dred[tid] = log(cLP[tid * 28] + 1e-8);
  __syncthreads();
  if (tid == 0) {
    double s = 0.0;
    for (int i = 0; i < 27; i++) s += dred[i];
    // final = sum over (n,c) of sum_log / (N * HALF_D) = /54
    atomicAdd(out, (float)(s / 54.0));
  }
}

// ---------------------------------------------------------------------------
extern "C" void kernel_launch(void* const* d_in, const int* in_sizes, int n_in,
                              void* d_out, int out_size, void* d_ws, size_t ws_size,
                              hipStream_t stream) {
  const float* logits = (const float*)d_in[0];
  const int* labels = (const int*)d_in[1];
  float* out = (float*)d_out;

  double* Gll = (double*)d_ws;
  double* Gpp = Gll + NCH * 729;
  double* Glp = Gpp + NCH * 729;
  double* sla = Glp + NCH * 729;
  double* spr = sla + NCH * 27;
  float* la_pool = (float*)(spr + NCH * 27);
  float* pr_pool = la_pool + NCH * NPOOL;

  size_t acc_bytes = (size_t)(3 * NCH * 729 + 2 * NCH * 27) * sizeof(double);
  hipMemsetAsync(d_ws, 0, acc_bytes, stream);
  hipMemsetAsync(d_out, 0, sizeof(float), stream);

  pool_kernel<<<(2 * NPOOL + 255) / 256, 256, 0, stream>>>(logits, labels, la_pool, pr_pool);
  sums_kernel<<<NCH * 27, 256, 0, stream>>>(la_pool, pr_pool, sla, spr);
  gram_kernel<<<NCH * 64 * 4, 256, 0, stream>>>(la_pool, pr_pool, Gll, Gpp, Glp);
  stage2_kernel<<<NCH, 128, 0, stream>>>(Gll, Gpp, Glp, sla, spr, out);
}

// Round 3
// 323.339 us; speedup vs baseline: 1.5397x; 1.4064x over previous
//
#include <hip/hip_runtime.h>
#include <math.h>

// Problem constants
#define NPOOL 110592          // 48^3 elements per channel after pooling
#define NVAL  97336           // 46^3 valid window positions
#define NCH   8               // N*C = 2*4 channels

typedef float v2f __attribute__((ext_vector_type(2)));

// Pair tables: unordered 2D-offset pairs (P <= Q), P,Q in [0,9)
__device__ const unsigned char c_pairP[45] = {
  0,0,0,0,0,0,0,0,0, 1,1,1,1,1,1,1,1, 2,2,2,2,2,2,2,
  3,3,3,3,3,3, 4,4,4,4,4, 5,5,5,5, 6,6,6, 7,7, 8};
__device__ const unsigned char c_pairQ[45] = {
  0,1,2,3,4,5,6,7,8, 1,2,3,4,5,6,7,8, 2,3,4,5,6,7,8,
  3,4,5,6,7,8, 4,5,6,7,8, 5,6,7,8, 6,7,8, 7,8, 8};
// 4 pair-groups: {0..11},{12..22},{23..33},{34..44}
__device__ const int c_gstart[5] = {0, 12, 23, 34, 45};

// ---------------------------------------------------------------------------
// Kernel 1: fused sigmoid/one-hot + 2x2x2 max-pool. float2/int2 coalesced.
// ---------------------------------------------------------------------------
__global__ __launch_bounds__(256) void pool_kernel(
    const float* __restrict__ logits, const int* __restrict__ labels,
    float* __restrict__ la_pool, float* __restrict__ pr_pool) {
  int t = blockIdx.x * 256 + threadIdx.x;
  if (t >= 2 * NPOOL) return;
  int Z = t % 48; int tmp = t / 48;
  int Y = tmp % 48; tmp /= 48;
  int X = tmp % 48; int n = tmp / 48;
  int sb = (2 * X) * 9216 + (2 * Y) * 96 + 2 * Z;   // spatial base in 96^3
  const int2* lb2 = (const int2*)(labels + n * 884736 + sb);
  int2 La = lb2[0], Lb = lb2[48], Lc = lb2[4608], Ld = lb2[4656];
  int ob = X * 2304 + Y * 48 + Z;
  #pragma unroll
  for (int c = 0; c < 4; c++) {
    const float2* lg2 = (const float2*)(logits + (size_t)(n * 4 + c) * 884736 + sb);
    float2 v0 = lg2[0], v1 = lg2[48], v2 = lg2[4608], v3 = lg2[4656];
    float mx = fmaxf(fmaxf(fmaxf(v0.x, v0.y), fmaxf(v1.x, v1.y)),
                     fmaxf(fmaxf(v2.x, v2.y), fmaxf(v3.x, v3.y)));
    float pr = 1.0f / (1.0f + expf(-mx)) + 1e-6f;
    float la = (La.x == c || La.y == c || Lb.x == c || Lb.y == c ||
                Lc.x == c || Lc.y == c || Ld.x == c || Ld.y == c) ? 1.0f : 0.0f;
    int oi = (n * 4 + c) * NPOOL + ob;
    la_pool[oi] = la;
    pr_pool[oi] = pr;
  }
}

// ---------------------------------------------------------------------------
// Kernel 2: row sums. Block = (channel, d, m-slice of 12167); 1728 blocks.
// fp64 atomics into zero-initialized sla/spr.
// ---------------------------------------------------------------------------
__global__ __launch_bounds__(256) void sums_kernel(
    const float* __restrict__ la_pool, const float* __restrict__ pr_pool,
    double* __restrict__ sla, double* __restrict__ spr) {
  int b = blockIdx.x;
  int slice = b & 7; int cd = b >> 3;
  int ch = cd / 27, d = cd % 27;
  int di = d / 9, dj = (d / 3) % 3, dk = d % 3;
  int off = di * 2304 + dj * 48 + dk;
  const float* A = la_pool + ch * NPOOL + off;
  const float* B = pr_pool + ch * NPOOL + off;
  int m0 = slice * 12167, m1 = m0 + 12167;      // 8 * 12167 = 97336
  double sa = 0.0, sb = 0.0;
  for (int m = m0 + (int)threadIdx.x; m < m1; m += 256) {
    int z = m % 46; int t2 = m / 46;
    int y = t2 % 46; int x = t2 / 46;
    int idx = x * 2304 + y * 48 + z;
    sa += (double)A[idx];
    sb += (double)B[idx];
  }
  __shared__ double ra[256], rb[256];
  ra[threadIdx.x] = sa; rb[threadIdx.x] = sb;
  __syncthreads();
  for (int s = 128; s > 0; s >>= 1) {
    if (threadIdx.x < (unsigned)s) {
      ra[threadIdx.x] += ra[threadIdx.x + s];
      rb[threadIdx.x] += rb[threadIdx.x + s];
    }
    __syncthreads();
  }
  if (threadIdx.x == 0) {
    atomicAdd(&sla[ch * 27 + d], ra[0]);
    atomicAdd(&spr[ch * 27 + d], rb[0]);
  }
}

// ---------------------------------------------------------------------------
// Kernel 3: Gram matrices via z-line correlation, float4 LDS reads, packed FMA.
// Block = (channel, 6x6 xy-tile, pair-group of ~11). 2048 blocks.
// All accumulators are individually-named registers -> nothing spillable.
// ---------------------------------------------------------------------------
#define LSTR 52   // padded z-line stride in floats (13 float4, rows 16B-aligned)

#define WIN(A0,A1,A2, B0,B1,B2, P0,P1,P2, Q0,Q1,Q2) do {              \
    v2f _b = {(B0),(B1)}, _p = {(P0),(P1)}, _q = {(Q0),(Q1)};         \
    v2f _x0 = {(A0),(A0)}, _x1 = {(A1),(A1)}, _x2 = {(A2),(A2)};      \
    vLL0 += _x0 * _b;  vLL1 += _x1 * _b;  vLL2 += _x2 * _b;           \
    vLA0 += _x0 * _q;  vLA1 += _x1 * _q;  vLA2 += _x2 * _q;           \
    sLL0 += (A0)*(B2); sLL1 += (A1)*(B2); sLL2 += (A2)*(B2);          \
    sLA0 += (A0)*(Q2); sLA1 += (A1)*(Q2); sLA2 += (A2)*(Q2);          \
    v2f _y0 = {(P0),(P0)}, _y1 = {(P1),(P1)}, _y2 = {(P2),(P2)};      \
    vPP0 += _y0 * _q;  vPP1 += _y1 * _q;  vPP2 += _y2 * _q;           \
    sPP0 += (P0)*(Q2); sPP1 += (P1)*(Q2); sPP2 += (P2)*(Q2);          \
    v2f _z0 = {(B0),(B0)}, _z1 = {(B1),(B1)}, _z2 = {(B2),(B2)};      \
    vLB0 += _z0 * _p;  vLB1 += _z1 * _p;  vLB2 += _z2 * _p;           \
    sLB0 += (B0)*(P2); sLB1 += (B1)*(P2); sLB2 += (B2)*(P2);          \
  } while (0)

__global__ __launch_bounds__(256) void gram_kernel(
    const float* __restrict__ la_pool, const float* __restrict__ pr_pool,
    double* __restrict__ Gll, double* __restrict__ Gpp, double* __restrict__ Glp) {
  __shared__ __align__(16) float Sla[64 * LSTR];
  __shared__ __align__(16) float Spr[64 * LSTR];
  __shared__ float red[12 * 36];

  int b = blockIdx.x;
  int g = b & 3;
  int tile = (b >> 2) & 63;
  int ch = b >> 8;
  int gstart = c_gstart[g];
  int gsize = c_gstart[g + 1] - gstart;
  int x0 = (tile & 7) * 6, y0 = (tile >> 3) * 6;
  const float* A = la_pool + ch * NPOOL;
  const float* B = pr_pool + ch * NPOOL;

  // Stage 8x8 rows of 48-float z-lines as float4 (rows beyond volume -> 0)
  for (int u = threadIdx.x; u < 64 * 12; u += 256) {
    int r = u / 12, zq = u - r * 12;
    int rx = r >> 3, ry = r & 7;
    int gx = x0 + rx, gy = y0 + ry;
    float4 va = {0.f, 0.f, 0.f, 0.f}, vb = va;
    if (gx < 48 && gy < 48) {
      int gi = gx * 2304 + gy * 48;
      va = ((const float4*)(A + gi))[zq];
      vb = ((const float4*)(B + gi))[zq];
    }
    ((float4*)Sla)[r * 13 + zq] = va;
    ((float4*)Spr)[r * 13 + zq] = vb;
  }
  for (int u = threadIdx.x; u < 12 * 36; u += 256) red[u] = 0.0f;
  __syncthreads();

  int ntask = gsize * 36;
  for (int task = threadIdx.x; task < ntask; task += 256) {
    int pairL = task % gsize;      // lanes spread across pairs (atomic decorrelation)
    int pos = task / gsize;        // 0..35
    int px = pos % 6, py = pos / 6;
    if (x0 + px >= 46 || y0 + py >= 46) continue;
    int pair = gstart + pairL;
    int P = c_pairP[pair], Q = c_pairQ[pair];
    int rowA = (px + P / 3) * 8 + (py + P % 3);
    int rowB = (px + Q / 3) * 8 + (py + Q % 3);
    const float4* laP4 = (const float4*)Sla + rowA * 13;
    const float4* laQ4 = (const float4*)Sla + rowB * 13;
    const float4* prP4 = (const float4*)Spr + rowA * 13;
    const float4* prQ4 = (const float4*)Spr + rowB * 13;

    v2f vLL0 = {0,0}, vLL1 = {0,0}, vLL2 = {0,0};
    v2f vPP0 = {0,0}, vPP1 = {0,0}, vPP2 = {0,0};
    v2f vLA0 = {0,0}, vLA1 = {0,0}, vLA2 = {0,0};
    v2f vLB0 = {0,0}, vLB1 = {0,0}, vLB2 = {0,0};
    float sLL0 = 0, sLL1 = 0, sLL2 = 0;
    float sPP0 = 0, sPP1 = 0, sPP2 = 0;
    float sLA0 = 0, sLA1 = 0, sLA2 = 0;
    float sLB0 = 0, sLB1 = 0, sLB2 = 0;

    // chunk 0: windows 0,1
    float4 wa = laP4[0], wb = laQ4[0], wp = prP4[0], wq = prQ4[0];
    WIN(wa.x, wa.y, wa.z,  wb.x, wb.y, wb.z,  wp.x, wp.y, wp.z,  wq.x, wq.y, wq.z);
    WIN(wa.y, wa.z, wa.w,  wb.y, wb.z, wb.w,  wp.y, wp.z, wp.w,  wq.y, wq.z, wq.w);
    float a0 = wa.z, a1 = wa.w, b0 = wb.z, b1 = wb.w;
    float p0 = wp.z, p1 = wp.w, q0 = wq.z, q1 = wq.w;
    // chunks 1..11: windows 4j-2 .. 4j+1  (total 2 + 44 = 46 windows)
    #pragma unroll 2
    for (int j = 1; j <= 11; j++) {
      wa = laP4[j]; wb = laQ4[j]; wp = prP4[j]; wq = prQ4[j];
      WIN(a0, a1, wa.x,      b0, b1, wb.x,      p0, p1, wp.x,      q0, q1, wq.x);
      WIN(a1, wa.x, wa.y,    b1, wb.x, wb.y,    p1, wp.x, wp.y,    q1, wq.x, wq.y);
      WIN(wa.x, wa.y, wa.z,  wb.x, wb.y, wb.z,  wp.x, wp.y, wp.z,  wq.x, wq.y, wq.z);
      WIN(wa.y, wa.z, wa.w,  wb.y, wb.z, wb.w,  wp.y, wp.z, wp.w,  wq.y, wq.z, wq.w);
      a0 = wa.z; a1 = wa.w; b0 = wb.z; b1 = wb.w;
      p0 = wp.z; p1 = wp.w; q0 = wq.z; q1 = wq.w;
    }

    int base = pairL * 36;
    atomicAdd(&red[base + 0],  vLL0.x); atomicAdd(&red[base + 1],  vLL0.y);
    atomicAdd(&red[base + 2],  sLL0);
    atomicAdd(&red[base + 3],  vLL1.x); atomicAdd(&red[base + 4],  vLL1.y);
    atomicAdd(&red[base + 5],  sLL1);
    atomicAdd(&red[base + 6],  vLL2.x); atomicAdd(&red[base + 7],  vLL2.y);
    atomicAdd(&red[base + 8],  sLL2);
    atomicAdd(&red[base + 9],  vPP0.x); atomicAdd(&red[base + 10], vPP0.y);
    atomicAdd(&red[base + 11], sPP0);
    atomicAdd(&red[base + 12], vPP1.x); atomicAdd(&red[base + 13], vPP1.y);
    atomicAdd(&red[base + 14], sPP1);
    atomicAdd(&red[base + 15], vPP2.x); atomicAdd(&red[base + 16], vPP2.y);
    atomicAdd(&red[base + 17], sPP2);
    atomicAdd(&red[base + 18], vLA0.x); atomicAdd(&red[base + 19], vLA0.y);
    atomicAdd(&red[base + 20], sLA0);
    atomicAdd(&red[base + 21], vLA1.x); atomicAdd(&red[base + 22], vLA1.y);
    atomicAdd(&red[base + 23], sLA1);
    atomicAdd(&red[base + 24], vLA2.x); atomicAdd(&red[base + 25], vLA2.y);
    atomicAdd(&red[base + 26], sLA2);
    if (P != Q) {
      atomicAdd(&red[base + 27], vLB0.x); atomicAdd(&red[base + 28], vLB0.y);
      atomicAdd(&red[base + 29], sLB0);
      atomicAdd(&red[base + 30], vLB1.x); atomicAdd(&red[base + 31], vLB1.y);
      atomicAdd(&red[base + 32], sLB1);
      atomicAdd(&red[base + 33], vLB2.x); atomicAdd(&red[base + 34], vLB2.y);
      atomicAdd(&red[base + 35], sLB2);
    }
  }
  __syncthreads();

  // Flush block partials to global fp64 accumulators
  for (int u = threadIdx.x; u < gsize * 36; u += 256) {
    int pairL = u / 36, slot = u - pairL * 36;
    int pair = gstart + pairL;
    int P = c_pairP[pair], Q = c_pairQ[pair];
    if (P == Q && slot >= 27) continue;
    float v = red[u];
    int kk = slot % 9, cat = slot / 9;
    int k1 = kk / 3, k2 = kk % 3;
    int d, e; double* dst;
    if (cat == 3) { d = Q * 3 + k1; e = P * 3 + k2; dst = Glp; }
    else {
      d = P * 3 + k1; e = Q * 3 + k2;
      dst = (cat == 0) ? Gll : (cat == 1) ? Gpp : Glp;
    }
    atomicAdd(&dst[ch * 729 + d * 27 + e], (double)v);
  }
}

// ---------------------------------------------------------------------------
// Kernel 4: per-channel 27x27 fp64 linear algebra. 256 threads per channel.
// Pivot-only (sqrt-free) eliminations, 1 barrier per step.
// Key identity: with raw eliminated columns c_j[i] and pivots p_j,
//   L[i][j] = c_j[i]/sqrt(p_j);   solving L W = B^T via s_i = sqrt(p_i) W[i]:
//   s_i[r] = B^T[i][r] - sum_{j<i} c_j[i] * (s_j[r]/p_j)
//   (W^T W)[i][j] = sum_t s_t[i] * s_t[j] / p_t
// ---------------------------------------------------------------------------
__global__ __launch_bounds__(256) void stage2_kernel(
    const double* __restrict__ Gll, const double* __restrict__ Gpp,
    const double* __restrict__ Glp, const double* __restrict__ sla,
    const double* __restrict__ spr, float* __restrict__ out) {
  __shared__ double cLL[729], cPP[729], cLP[729], W[729], Vt[729];
  __shared__ double dpiv[27], ipiv[27];
  int ch = blockIdx.x, tid = threadIdx.x;
  const double Minv = 1.0 / (double)NVAL;
  const double alpha = 5e-4;
  const double* gll = Gll + ch * 729;
  const double* gpp = Gpp + ch * 729;
  const double* glp = Glp + ch * 729;
  const double* sl = sla + ch * 27;
  const double* sp = spr + ch * 27;

  // Center + symmetrize (upper-2D-block cells are authoritative)
  for (int u = tid; u < 729; u += 256) {
    int d = u / 27, e = u - d * 27;
    int Pd = d / 3, Pe = e / 3;
    double vll = (Pd <= Pe) ? gll[d * 27 + e] : gll[e * 27 + d];
    double vpp = (Pd <= Pe) ? gpp[d * 27 + e] : gpp[e * 27 + d];
    cLL[u] = vll - sl[d] * sl[e] * Minv;
    cPP[u] = vpp - sp[d] * sp[e] * Minv + ((d == e) ? alpha : 0.0);
    cLP[u] = glp[u] - sl[d] * sp[e] * Minv;
  }
  __syncthreads();

  // Elimination 1 on cPP (lower triangle, raw columns kept, pivots recorded)
  for (int k = 0; k < 27; k++) {
    double d = cPP[k * 28];
    if (tid == 0) dpiv[k] = d;
    double dinv = 1.0 / d;
    for (int u = tid; u < 729; u += 256) {
      int i = u / 27, j = u - i * 27;
      if (i > k && j > k && j <= i)
        cPP[u] -= cPP[i * 27 + k] * cPP[j * 27 + k] * dinv;
    }
    __syncthreads();
  }
  if (tid < 27) ipiv[tid] = 1.0 / dpiv[tid];
  __syncthreads();

  // Forward substitution (unscaled): thread r owns column r.
  // W[i][r] = s_i ; Vt[i][r] = s_i / p_i
  if (tid < 27) {
    int r = tid;
    for (int i = 0; i < 27; i++) {
      double s = cLP[r * 27 + i];            // B^T[i][r] = B[r][i]
      for (int j = 0; j < i; j++) s -= cPP[i * 27 + j] * Vt[j * 27 + r];
      W[i * 27 + r] = s;
      Vt[i * 27 + r] = s * ipiv[i];
    }
  }
  __syncthreads();

  // appro_var + alpha*I (lower triangle only) -> overwrite cLP
  for (int u = tid; u < 729; u += 256) {
    int i = u / 27, j = u - i * 27;
    if (j > i) continue;
    double s = 0.0;
    for (int t2 = 0; t2 < 27; t2++) s += Vt[t2 * 27 + i] * W[t2 * 27 + j];
    cLP[u] = cLL[u] - s + ((i == j) ? alpha : 0.0);
  }
  __syncthreads();

  // Elimination 2: only need pivots -> chol diag = sqrt(pivot)
  double sum_log = 0.0;
  for (int k = 0; k < 27; k++) {
    double d = cLP[k * 28];
    sum_log += log(sqrt(d) + 1e-8);
    double dinv = 1.0 / d;
    for (int u = tid; u < 729; u += 256) {
      int i = u / 27, j = u - i * 27;
      if (i > k && j > k && j <= i)
        cLP[u] -= cLP[i * 27 + k] * cLP[j * 27 + k] * dinv;
    }
    __syncthreads();
  }

  if (tid == 0) atomicAdd(out, (float)(sum_log / 54.0));
}

// ---------------------------------------------------------------------------
extern "C" void kernel_launch(void* const* d_in, const int* in_sizes, int n_in,
                              void* d_out, int out_size, void* d_ws, size_t ws_size,
                              hipStream_t stream) {
  const float* logits = (const float*)d_in[0];
  const int* labels = (const int*)d_in[1];
  float* out = (float*)d_out;

  double* Gll = (double*)d_ws;
  double* Gpp = Gll + NCH * 729;
  double* Glp = Gpp + NCH * 729;
  double* sla = Glp + NCH * 729;
  double* spr = sla + NCH * 27;
  float* la_pool = (float*)(spr + NCH * 27);
  float* pr_pool = la_pool + NCH * NPOOL;

  size_t acc_bytes = (size_t)(3 * NCH * 729 + 2 * NCH * 27) * sizeof(double);
  hipMemsetAsync(d_ws, 0, acc_bytes, stream);
  hipMemsetAsync(d_out, 0, sizeof(float), stream);

  pool_kernel<<<(2 * NPOOL + 255) / 256, 256, 0, stream>>>(logits, labels, la_pool, pr_pool);
  sums_kernel<<<NCH * 27 * 8, 256, 0, stream>>>(la_pool, pr_pool, sla, spr);
  gram_kernel<<<NCH * 64 * 4, 256, 0, stream>>>(la_pool, pr_pool, Gll, Gpp, Glp);
  stage2_kernel<<<NCH, 256, 0, stream>>>(Gll, Gpp, Glp, sla, spr, out);
}

// Round 4
// 142.298 us; speedup vs baseline: 3.4985x; 2.2723x over previous
//
#include <hip/hip_runtime.h>
#include <math.h>

// Problem constants
#define NVAL  97336           // 46^3 valid window positions
#define NCH   8               // N*C = 2*4 channels

typedef unsigned short u16;
typedef __attribute__((ext_vector_type(8))) short bf16x8;
typedef __attribute__((ext_vector_type(4))) float f32x4;
typedef __attribute__((ext_vector_type(4))) unsigned int u32x4;

// LDS staging geometry (gram kernel)
#define LINE_B 336            // 3 copies * 112 B per (x,y,vol) z-line
#define COPY_B 112            // 48 bf16 (96 B) + 16 B pad (bank spread)
#define VOL_B  21504          // 64 lines * 336
#define SHIFT_LINE_U16 144    // global pre-shifted line: 3 copies * 48 u16

// ---------------------------------------------------------------------------
// Kernel 1: fused sigmoid/one-hot + 2x2x2 max-pool -> bf16, written as 3
// z-pre-shifted copies per line: copy dz slot s holds vol[z = s+dz].
// Tail slots (s+dz>47) stay zero via the memset.
// ---------------------------------------------------------------------------
__global__ __launch_bounds__(256) void pool_kernel(
    const float* __restrict__ logits, const int* __restrict__ labels,
    u16* __restrict__ shifted) {
  int t = blockIdx.x * 256 + threadIdx.x;
  if (t >= 2 * 110592) return;
  int Z = t % 48; int tmp = t / 48;
  int Y = tmp % 48; tmp /= 48;
  int X = tmp % 48; int n = tmp / 48;
  int sb = (2 * X) * 9216 + (2 * Y) * 96 + 2 * Z;
  const int2* lb2 = (const int2*)(labels + n * 884736 + sb);
  int2 La = lb2[0], Lb = lb2[48], Lc = lb2[4608], Ld = lb2[4656];
  #pragma unroll
  for (int c = 0; c < 4; c++) {
    const float2* lg2 = (const float2*)(logits + (size_t)(n * 4 + c) * 884736 + sb);
    float2 v0 = lg2[0], v1 = lg2[48], v2 = lg2[4608], v3 = lg2[4656];
    float mx = fmaxf(fmaxf(fmaxf(v0.x, v0.y), fmaxf(v1.x, v1.y)),
                     fmaxf(fmaxf(v2.x, v2.y), fmaxf(v3.x, v3.y)));
    // max(sigmoid) == sigmoid(max); +1e-6 commutes with max
    float pr = 1.0f / (1.0f + expf(-mx)) + 1e-6f;
    int la = (La.x == c || La.y == c || Lb.x == c || Lb.y == c ||
              Lc.x == c || Lc.y == c || Ld.x == c || Ld.y == c);
    u16 la16 = la ? (u16)0x3F80 : (u16)0;         // bf16(1.0)
    unsigned int u = __float_as_uint(pr);          // round-to-nearest-even bf16
    u16 pr16 = (u16)((u + 0x7FFF + ((u >> 16) & 1)) >> 16);
    int ch = n * 4 + c;
    size_t lbase = ((size_t)(ch * 2 + 0) * 2304 + X * 48 + Y) * SHIFT_LINE_U16;
    size_t pbase = ((size_t)(ch * 2 + 1) * 2304 + X * 48 + Y) * SHIFT_LINE_U16;
    #pragma unroll
    for (int dz = 0; dz < 3; dz++) {
      int s = Z - dz;
      if (s >= 0) {
        shifted[lbase + dz * 48 + s] = la16;
        shifted[pbase + dz * 48 + s] = pr16;
      }
    }
  }
}

// ---------------------------------------------------------------------------
// Kernel 2: Gram via MFMA. W rows 0-26 = la shifts, 27-53 = pr shifts,
// 54 = ones (row sums for free), 55-63 = zero. G = (mask.W) W^T, upper
// triangle as 10 16x16 tiles. Block = (ch, 6x6 xy-tile of base positions);
// K = tw*th lines * 48 z. A-operand gets z-mask (z=46,47 zeroed).
// Verified layouts: A[m=lane&15][k=(lane>>4)*8+j]; C/D col=lane&15,
// row=(lane>>4)*4+reg (learn_hip m89/m91/m118).
// ---------------------------------------------------------------------------
#define MFMA16(A, B, C) __builtin_amdgcn_mfma_f32_16x16x32_bf16((A), (B), (C), 0, 0, 0)

#define STEP(BA, AM) do {                                                  \
    int _ba = (BA);                                                        \
    u32x4 ub0 = *(const u32x4*)(smem + _ba + laneC0);                      \
    u32x4 ub1 = *(const u32x4*)(smem + _ba + laneC1);                      \
    u32x4 ub2 = *(const u32x4*)(smem + _ba + laneC2);                      \
    u32x4 ub3 = *(const u32x4*)(smem + _ba + laneC3);                      \
    ub3 = iszero ? zer4 : (isones ? one4 : ub3);                           \
    u32x4 ua0 = ub0, ua1 = ub1, ua2 = ub2, ua3 = ub3;                      \
    ua0.w &= (AM); ua1.w &= (AM); ua2.w &= (AM); ua3.w &= (AM);            \
    bf16x8 A0 = __builtin_bit_cast(bf16x8, ua0);                           \
    bf16x8 A1 = __builtin_bit_cast(bf16x8, ua1);                           \
    bf16x8 A2 = __builtin_bit_cast(bf16x8, ua2);                           \
    bf16x8 A3 = __builtin_bit_cast(bf16x8, ua3);                           \
    bf16x8 B0 = __builtin_bit_cast(bf16x8, ub0);                           \
    bf16x8 B1 = __builtin_bit_cast(bf16x8, ub1);                           \
    bf16x8 B2 = __builtin_bit_cast(bf16x8, ub2);                           \
    bf16x8 B3 = __builtin_bit_cast(bf16x8, ub3);                           \
    acc0 = MFMA16(A0, B0, acc0);  acc1 = MFMA16(A0, B1, acc1);             \
    acc2 = MFMA16(A0, B2, acc2);  acc3 = MFMA16(A0, B3, acc3);             \
    acc4 = MFMA16(A1, B1, acc4);  acc5 = MFMA16(A1, B2, acc5);             \
    acc6 = MFMA16(A1, B3, acc6);  acc7 = MFMA16(A2, B2, acc7);             \
    acc8 = MFMA16(A2, B3, acc8);  acc9 = MFMA16(A3, B3, acc9);             \
  } while (0)

__global__ __launch_bounds__(256) void gram_kernel(
    const u16* __restrict__ shifted, float* __restrict__ partials) {
  __shared__ __align__(16) unsigned char smem[43008];
  int bx = blockIdx.x;
  int ch = bx >> 6, xt = (bx >> 3) & 7, yt = bx & 7;
  int X0 = xt * 6, Y0 = yt * 6;
  int tw = (xt == 7) ? 4 : 6, th = (yt == 7) ? 4 : 6;
  int sw = tw + 2, sh = th + 2;
  int tid = threadIdx.x;

  // Stage (tw+2)x(th+2) lines x 2 vols, 3 pre-shifted copies each, into LDS
  const u16* base = shifted + (size_t)ch * 2 * 2304 * SHIFT_LINE_U16;
  int njobs = 2 * sw * sh * 18;                  // 18 x 16B chunks per line
  for (int j = tid; j < njobs; j += 256) {
    int chunk = j % 18; int li = j / 18;
    int sy = li % sh; int t2 = li / sh; int sx = t2 % sw; int vol = t2 / sw;
    const u32x4* src = (const u32x4*)(base +
        ((size_t)vol * 2304 + (X0 + sx) * 48 + (Y0 + sy)) * SHIFT_LINE_U16);
    u32x4 v = src[chunk];
    int dz = chunk / 6, cc = chunk - dz * 6;
    *(u32x4*)(smem + vol * VOL_B + (sx * sh + sy) * LINE_B + dz * COPY_B + cc * 16) = v;
  }
  __syncthreads();

  int lane = tid & 63, w = tid >> 6;
  int q = lane >> 4, rlo = lane & 15;
  // Per-lane fragment base offset: row -> (vol, shift) -> staged line + copy
#define LANEC(F) ({ int _r = (F) * 16 + rlo; int _vol = 0, _s = 0;           \
    if (_r < 27) { _s = _r; } else if (_r < 54) { _vol = 1; _s = _r - 27; }  \
    int _dx = _s / 9, _dy = (_s / 3) % 3, _dz = _s % 3;                      \
    _vol * VOL_B + (_dx * sh + _dy) * LINE_B + _dz * COPY_B; })
  int laneC0 = LANEC(0), laneC1 = LANEC(1), laneC2 = LANEC(2), laneC3 = LANEC(3);
  // A-side z-mask: kill z=46,47 (invalid windows). ctype1: quad1 j=6,7;
  // ctype2: quad3 j=6,7 -> zero dword 3 of the fragment.
  unsigned int am1 = (q == 1) ? 0u : ~0u;
  unsigned int am2 = (q == 3) ? 0u : ~0u;
  bool isones = (rlo == 6);    // frag3 row 54 = ones
  bool iszero = (rlo > 6);     // frag3 rows 55-63 = zero
  u32x4 one4 = {0x3F803F80u, 0x3F803F80u, 0x3F803F80u, 0x3F803F80u};
  u32x4 zer4 = {0u, 0u, 0u, 0u};

  f32x4 acc0 = {0,0,0,0}, acc1 = {0,0,0,0}, acc2 = {0,0,0,0}, acc3 = {0,0,0,0};
  f32x4 acc4 = {0,0,0,0}, acc5 = {0,0,0,0}, acc6 = {0,0,0,0}, acc7 = {0,0,0,0};
  f32x4 acc8 = {0,0,0,0}, acc9 = {0,0,0,0};

  // K-loop: pairs of z-lines (96 z = 3 k-chunks of 32), split across 4 waves
  int npl = (tw * th) >> 1;
  for (int pl = w; pl < npl; pl += 4) {
    int L0 = 2 * pl, L1 = L0 + 1;
    int lx0 = L0 / th, ly0 = L0 - lx0 * th;
    int lx1 = L1 / th, ly1 = L1 - lx1 * th;
    int U0 = (lx0 * sh + ly0) * LINE_B;
    int U1 = (lx1 * sh + ly1) * LINE_B;
    STEP(U0 + 16 * q, ~0u);                                    // z 0..31 of L0
    STEP((q < 2) ? (U0 + 64 + 16 * q) : (U1 + 16 * q - 32), am1); // 32..47|0..15
    STEP(U1 + 32 + 16 * q, am2);                               // z 16..47 of L1
  }
  __syncthreads();

  // Flush wave partials to LDS (reuse staging area), reduce, store fp32
  float* Pf = (float*)smem;
#define FL(T, A) { float* _qp = Pf + w * 2560 + (T) * 256 + lane;            \
    _qp[0] = (A).x; _qp[64] = (A).y; _qp[128] = (A).z; _qp[192] = (A).w; }
  FL(0, acc0) FL(1, acc1) FL(2, acc2) FL(3, acc3) FL(4, acc4)
  FL(5, acc5) FL(6, acc6) FL(7, acc7) FL(8, acc8) FL(9, acc9)
  __syncthreads();
  float* dst = partials + (size_t)(ch * 64 + xt * 8 + yt) * 2560;
  for (int u2 = tid; u2 < 2560; u2 += 256)
    dst[u2] = Pf[u2] + Pf[u2 + 2560] + Pf[u2 + 5120] + Pf[u2 + 7680];
}

// ---------------------------------------------------------------------------
// Kernel 3: sum 64 block-partials per channel in fp64.
// ---------------------------------------------------------------------------
__global__ __launch_bounds__(256) void reduce_kernel(
    const float* __restrict__ partials, double* __restrict__ Gsum) {
  int b = blockIdx.x; int ch = b / 10;
  int so = (b - ch * 10) * 256 + threadIdx.x;
  const float* p = partials + (size_t)ch * 64 * 2560 + so;
  double s = 0.0;
  for (int t = 0; t < 64; t++) s += (double)p[t * 2560];
  Gsum[ch * 2560 + so] = s;
}

// ---------------------------------------------------------------------------
// Kernel 4: per-channel 27x27 fp64 algebra (validated in R3), reading the
// MFMA-slot-encoded 54x54 Gram. Row/col 54 = sums row.
// ---------------------------------------------------------------------------
__device__ inline double g54(const double* __restrict__ G, int R, int C) {
  int I = R >> 4, J = C >> 4;
  if (I > J) { int tt = R; R = C; C = tt; I = R >> 4; J = C >> 4; }
  int tile = 4 * I - ((I * (I - 1)) >> 1) + (J - I);
  int r = R & 15, c = C & 15;
  return G[tile * 256 + (r & 3) * 64 + ((r >> 2) << 4) + c];
}

__global__ __launch_bounds__(256) void stage2_kernel(
    const double* __restrict__ Gsum, float* __restrict__ out) {
  __shared__ double cLL[729], cPP[729], cLP[729], W[729], Vt[729];
  __shared__ double slv[27], spv[27], dpiv[27], ipiv[27];
  int ch = blockIdx.x, tid = threadIdx.x;
  const double Minv = 1.0 / (double)NVAL;
  const double alpha = 5e-4;
  const double* G = Gsum + ch * 2560;

  if (tid < 27) { slv[tid] = g54(G, tid, 54); spv[tid] = g54(G, 27 + tid, 54); }
  __syncthreads();
  for (int u = tid; u < 729; u += 256) {
    int d = u / 27, e = u - d * 27;
    cLL[u] = g54(G, d, e) - slv[d] * slv[e] * Minv;
    cPP[u] = g54(G, 27 + d, 27 + e) - spv[d] * spv[e] * Minv + ((d == e) ? alpha : 0.0);
    cLP[u] = g54(G, d, 27 + e) - slv[d] * spv[e] * Minv;
  }
  __syncthreads();

  // Elimination 1 on cPP (sqrt-free, raw columns + pivots)
  for (int k = 0; k < 27; k++) {
    double d = cPP[k * 28];
    if (tid == 0) dpiv[k] = d;
    double dinv = 1.0 / d;
    for (int u = tid; u < 729; u += 256) {
      int i = u / 27, j = u - i * 27;
      if (i > k && j > k && j <= i)
        cPP[u] -= cPP[i * 27 + k] * cPP[j * 27 + k] * dinv;
    }
    __syncthreads();
  }
  if (tid < 27) ipiv[tid] = 1.0 / dpiv[tid];
  __syncthreads();

  // Forward substitution (unscaled): thread r owns column r
  if (tid < 27) {
    int r = tid;
    for (int i = 0; i < 27; i++) {
      double s = cLP[r * 27 + i];
      for (int j = 0; j < i; j++) s -= cPP[i * 27 + j] * Vt[j * 27 + r];
      W[i * 27 + r] = s;
      Vt[i * 27 + r] = s * ipiv[i];
    }
  }
  __syncthreads();

  // appro_var + alpha*I (lower triangle)
  for (int u = tid; u < 729; u += 256) {
    int i = u / 27, j = u - i * 27;
    if (j > i) continue;
    double s = 0.0;
    for (int t2 = 0; t2 < 27; t2++) s += Vt[t2 * 27 + i] * W[t2 * 27 + j];
    cLP[u] = cLL[u] - s + ((i == j) ? alpha : 0.0);
  }
  __syncthreads();

  // Elimination 2: chol diag = sqrt(pivot)
  double sum_log = 0.0;
  for (int k = 0; k < 27; k++) {
    double d = cLP[k * 28];
    sum_log += log(sqrt(d) + 1e-8);
    double dinv = 1.0 / d;
    for (int u = tid; u < 729; u += 256) {
      int i = u / 27, j = u - i * 27;
      if (i > k && j > k && j <= i)
        cLP[u] -= cLP[i * 27 + k] * cLP[j * 27 + k] * dinv;
    }
    __syncthreads();
  }
  if (tid == 0) atomicAdd(out, (float)(sum_log / 54.0));
}

// ---------------------------------------------------------------------------
extern "C" void kernel_launch(void* const* d_in, const int* in_sizes, int n_in,
                              void* d_out, int out_size, void* d_ws, size_t ws_size,
                              hipStream_t stream) {
  const float* logits = (const float*)d_in[0];
  const int* labels = (const int*)d_in[1];
  float* out = (float*)d_out;

  // ws layout: Gsum fp64 (160 KB) | partials fp32 (5 MB) | shifted bf16 (10.6 MB)
  double* Gsum = (double*)d_ws;
  float* partials = (float*)((char*)d_ws + 163840);
  u16* shifted = (u16*)((char*)d_ws + 163840 + 5242880);

  hipMemsetAsync(shifted, 0, (size_t)NCH * 2 * 2304 * SHIFT_LINE_U16 * 2, stream);
  hipMemsetAsync(d_out, 0, sizeof(float), stream);

  pool_kernel<<<864, 256, 0, stream>>>(logits, labels, shifted);
  gram_kernel<<<512, 256, 0, stream>>>(shifted, partials);
  reduce_kernel<<<80, 256, 0, stream>>>(partials, Gsum);
  stage2_kernel<<<NCH, 256, 0, stream>>>(Gsum, out);
}

// Round 5
// 136.524 us; speedup vs baseline: 3.6465x; 1.0423x over previous
//
#include <hip/hip_runtime.h>
#include <math.h>

// Problem constants
#define NVAL  97336           // 46^3 valid window positions
#define NCH   8               // N*C = 2*4 channels

typedef unsigned short u16;
typedef __attribute__((ext_vector_type(8))) short bf16x8;
typedef __attribute__((ext_vector_type(4))) float f32x4;
typedef __attribute__((ext_vector_type(4))) unsigned int u32x4;

// LDS staging geometry (gram kernel)
#define LINE_B 336            // 3 copies * 112 B per (x,y,vol) z-line
#define COPY_B 112            // 48 bf16 (96 B) + 16 B pad (bank spread)
#define VOL_B  21504          // 64 lines * 336
#define SHIFT_LINE_U16 144    // global pre-shifted line: 3 copies * 48 u16

// ---------------------------------------------------------------------------
// Kernel 1: fused sigmoid/one-hot + 2x2x2 max-pool -> bf16, written as 3
// z-pre-shifted copies per line: copy dz slot s holds vol[z = s+dz].
// Tail slots (s+dz>47) are zero-filled explicitly (no memset needed).
// ---------------------------------------------------------------------------
__global__ __launch_bounds__(256) void pool_kernel(
    const float* __restrict__ logits, const int* __restrict__ labels,
    u16* __restrict__ shifted) {
  int t = blockIdx.x * 256 + threadIdx.x;
  if (t >= 2 * 110592) return;
  int Z = t % 48; int tmp = t / 48;
  int Y = tmp % 48; tmp /= 48;
  int X = tmp % 48; int n = tmp / 48;
  int sb = (2 * X) * 9216 + (2 * Y) * 96 + 2 * Z;
  const int2* lb2 = (const int2*)(labels + n * 884736 + sb);
  int2 La = lb2[0], Lb = lb2[48], Lc = lb2[4608], Ld = lb2[4656];
  #pragma unroll
  for (int c = 0; c < 4; c++) {
    const float2* lg2 = (const float2*)(logits + (size_t)(n * 4 + c) * 884736 + sb);
    float2 v0 = lg2[0], v1 = lg2[48], v2 = lg2[4608], v3 = lg2[4656];
    float mx = fmaxf(fmaxf(fmaxf(v0.x, v0.y), fmaxf(v1.x, v1.y)),
                     fmaxf(fmaxf(v2.x, v2.y), fmaxf(v3.x, v3.y)));
    // max(sigmoid) == sigmoid(max); +1e-6 commutes with max
    float pr = 1.0f / (1.0f + expf(-mx)) + 1e-6f;
    int la = (La.x == c || La.y == c || Lb.x == c || Lb.y == c ||
              Lc.x == c || Lc.y == c || Ld.x == c || Ld.y == c);
    u16 la16 = la ? (u16)0x3F80 : (u16)0;         // bf16(1.0)
    unsigned int u = __float_as_uint(pr);          // round-to-nearest-even bf16
    u16 pr16 = (u16)((u + 0x7FFF + ((u >> 16) & 1)) >> 16);
    int ch = n * 4 + c;
    size_t lbase = ((size_t)(ch * 2 + 0) * 2304 + X * 48 + Y) * SHIFT_LINE_U16;
    size_t pbase = ((size_t)(ch * 2 + 1) * 2304 + X * 48 + Y) * SHIFT_LINE_U16;
    #pragma unroll
    for (int dz = 0; dz < 3; dz++) {
      int s = Z - dz;
      u16 lo = la16, po = pr16;
      if (s < 0) { s = 47 - (dz - 1 - Z); lo = 0; po = 0; }  // tail zero slots
      shifted[lbase + dz * 48 + s] = lo;
      shifted[pbase + dz * 48 + s] = po;
    }
  }
}

// ---------------------------------------------------------------------------
// Kernel 2: Gram via MFMA. W rows 0-26 = la shifts, 27-53 = pr shifts,
// 54 = ones (row sums for free), 55-63 = zero. G = (mask.W) W^T, upper
// triangle as 10 16x16 tiles. Block = (ch, 6x6 xy-tile of base positions).
// ---------------------------------------------------------------------------
#define MFMA16(A, B, C) __builtin_amdgcn_mfma_f32_16x16x32_bf16((A), (B), (C), 0, 0, 0)

#define STEP(BA, AM) do {                                                  \
    int _ba = (BA);                                                        \
    u32x4 ub0 = *(const u32x4*)(smem + _ba + laneC0);                      \
    u32x4 ub1 = *(const u32x4*)(smem + _ba + laneC1);                      \
    u32x4 ub2 = *(const u32x4*)(smem + _ba + laneC2);                      \
    u32x4 ub3 = *(const u32x4*)(smem + _ba + laneC3);                      \
    ub3 = iszero ? zer4 : (isones ? one4 : ub3);                           \
    u32x4 ua0 = ub0, ua1 = ub1, ua2 = ub2, ua3 = ub3;                      \
    ua0.w &= (AM); ua1.w &= (AM); ua2.w &= (AM); ua3.w &= (AM);            \
    bf16x8 A0 = __builtin_bit_cast(bf16x8, ua0);                           \
    bf16x8 A1 = __builtin_bit_cast(bf16x8, ua1);                           \
    bf16x8 A2 = __builtin_bit_cast(bf16x8, ua2);                           \
    bf16x8 A3 = __builtin_bit_cast(bf16x8, ua3);                           \
    bf16x8 B0 = __builtin_bit_cast(bf16x8, ub0);                           \
    bf16x8 B1 = __builtin_bit_cast(bf16x8, ub1);                           \
    bf16x8 B2 = __builtin_bit_cast(bf16x8, ub2);                           \
    bf16x8 B3 = __builtin_bit_cast(bf16x8, ub3);                           \
    acc0 = MFMA16(A0, B0, acc0);  acc1 = MFMA16(A0, B1, acc1);             \
    acc2 = MFMA16(A0, B2, acc2);  acc3 = MFMA16(A0, B3, acc3);             \
    acc4 = MFMA16(A1, B1, acc4);  acc5 = MFMA16(A1, B2, acc5);             \
    acc6 = MFMA16(A1, B3, acc6);  acc7 = MFMA16(A2, B2, acc7);             \
    acc8 = MFMA16(A2, B3, acc8);  acc9 = MFMA16(A3, B3, acc9);             \
  } while (0)

__global__ __launch_bounds__(256) void gram_kernel(
    const u16* __restrict__ shifted, float* __restrict__ partials) {
  __shared__ __align__(16) unsigned char smem[43008];
  int bx = blockIdx.x;
  int ch = bx >> 6, xt = (bx >> 3) & 7, yt = bx & 7;
  int X0 = xt * 6, Y0 = yt * 6;
  int tw = (xt == 7) ? 4 : 6, th = (yt == 7) ? 4 : 6;
  int sw = tw + 2, sh = th + 2;
  int tid = threadIdx.x;

  // Stage (tw+2)x(th+2) lines x 2 vols, 3 pre-shifted copies each, into LDS
  const u16* base = shifted + (size_t)ch * 2 * 2304 * SHIFT_LINE_U16;
  int njobs = 2 * sw * sh * 18;                  // 18 x 16B chunks per line
  for (int j = tid; j < njobs; j += 256) {
    int chunk = j % 18; int li = j / 18;
    int sy = li % sh; int t2 = li / sh; int sx = t2 % sw; int vol = t2 / sw;
    const u32x4* src = (const u32x4*)(base +
        ((size_t)vol * 2304 + (X0 + sx) * 48 + (Y0 + sy)) * SHIFT_LINE_U16);
    u32x4 v = src[chunk];
    int dz = chunk / 6, cc = chunk - dz * 6;
    *(u32x4*)(smem + vol * VOL_B + (sx * sh + sy) * LINE_B + dz * COPY_B + cc * 16) = v;
  }
  __syncthreads();

  int lane = tid & 63, w = tid >> 6;
  int q = lane >> 4, rlo = lane & 15;
#define LANEC(F) ({ int _r = (F) * 16 + rlo; int _vol = 0, _s = 0;           \
    if (_r < 27) { _s = _r; } else if (_r < 54) { _vol = 1; _s = _r - 27; }  \
    int _dx = _s / 9, _dy = (_s / 3) % 3, _dz = _s % 3;                      \
    _vol * VOL_B + (_dx * sh + _dy) * LINE_B + _dz * COPY_B; })
  int laneC0 = LANEC(0), laneC1 = LANEC(1), laneC2 = LANEC(2), laneC3 = LANEC(3);
  unsigned int am1 = (q == 1) ? 0u : ~0u;
  unsigned int am2 = (q == 3) ? 0u : ~0u;
  bool isones = (rlo == 6);    // frag3 row 54 = ones
  bool iszero = (rlo > 6);     // frag3 rows 55-63 = zero
  u32x4 one4 = {0x3F803F80u, 0x3F803F80u, 0x3F803F80u, 0x3F803F80u};
  u32x4 zer4 = {0u, 0u, 0u, 0u};

  f32x4 acc0 = {0,0,0,0}, acc1 = {0,0,0,0}, acc2 = {0,0,0,0}, acc3 = {0,0,0,0};
  f32x4 acc4 = {0,0,0,0}, acc5 = {0,0,0,0}, acc6 = {0,0,0,0}, acc7 = {0,0,0,0};
  f32x4 acc8 = {0,0,0,0}, acc9 = {0,0,0,0};

  int npl = (tw * th) >> 1;
  for (int pl = w; pl < npl; pl += 4) {
    int L0 = 2 * pl, L1 = L0 + 1;
    int lx0 = L0 / th, ly0 = L0 - lx0 * th;
    int lx1 = L1 / th, ly1 = L1 - lx1 * th;
    int U0 = (lx0 * sh + ly0) * LINE_B;
    int U1 = (lx1 * sh + ly1) * LINE_B;
    STEP(U0 + 16 * q, ~0u);
    STEP((q < 2) ? (U0 + 64 + 16 * q) : (U1 + 16 * q - 32), am1);
    STEP(U1 + 32 + 16 * q, am2);
  }
  __syncthreads();

  float* Pf = (float*)smem;
#define FL(T, A) { float* _qp = Pf + w * 2560 + (T) * 256 + lane;            \
    _qp[0] = (A).x; _qp[64] = (A).y; _qp[128] = (A).z; _qp[192] = (A).w; }
  FL(0, acc0) FL(1, acc1) FL(2, acc2) FL(3, acc3) FL(4, acc4)
  FL(5, acc5) FL(6, acc6) FL(7, acc7) FL(8, acc8) FL(9, acc9)
  __syncthreads();
  float* dst = partials + (size_t)(ch * 64 + xt * 8 + yt) * 2560;
  for (int u2 = tid; u2 < 2560; u2 += 256)
    dst[u2] = Pf[u2] + Pf[u2 + 2560] + Pf[u2 + 5120] + Pf[u2 + 7680];
}

// ---------------------------------------------------------------------------
// Kernel 3: sum 64 block-partials per channel in fp64.
// ---------------------------------------------------------------------------
__global__ __launch_bounds__(256) void reduce_kernel(
    const float* __restrict__ partials, double* __restrict__ Gsum) {
  int b = blockIdx.x; int ch = b / 10;
  int so = (b - ch * 10) * 256 + threadIdx.x;
  const float* p = partials + (size_t)ch * 64 * 2560 + so;
  double s = 0.0;
  for (int t = 0; t < 64; t++) s += (double)p[t * 2560];
  Gsum[ch * 2560 + so] = s;
}

// ---------------------------------------------------------------------------
// Kernel 4: per-channel algebra as ONE 54-step bordered elimination.
// M = [[pr_cov+aI, B^T],[B, la_cov+aI]] (B = la_pr_cov). After 27 steps the
// trailing block is appro_var+aI; pivots 27..53 = chol(appro_var+aI) diag^2.
// One barrier per step; next pivot's 1/d computed by its owner pre-barrier.
// ---------------------------------------------------------------------------
#define MS 55   // row stride (doubles); 2-way LDS aliasing only
__device__ inline double g54(const double* __restrict__ G, int R, int C) {
  int I = R >> 4, J = C >> 4;
  if (I > J) { int tt = R; R = C; C = tt; I = R >> 4; J = C >> 4; }
  int tile = 4 * I - ((I * (I - 1)) >> 1) + (J - I);
  int r = R & 15, c = C & 15;
  return G[tile * 256 + (r & 3) * 64 + ((r >> 2) << 4) + c];
}

__global__ __launch_bounds__(256) void stage2_kernel(
    const double* __restrict__ Gsum, float* __restrict__ out) {
  __shared__ double M[54 * MS];
  __shared__ double slv[27], spv[27], piv[54], idiv[54], lred[27];
  int ch = blockIdx.x, tid = threadIdx.x;
  const double Minv = 1.0 / (double)NVAL;
  const double alpha = 5e-4;
  const double* G = Gsum + ch * 2560;

  if (tid < 27) { slv[tid] = g54(G, tid, 54); spv[tid] = g54(G, 27 + tid, 54); }
  __syncthreads();
  // Build bordered matrix: indices 0..26 = pr dims, 27..53 = la dims
  for (int u = tid; u < 54 * 54; u += 256) {
    int a = u / 54, b = u - a * 54;
    double v;
    if (a < 27 && b < 27) {
      v = g54(G, 27 + a, 27 + b) - spv[a] * spv[b] * Minv + ((a == b) ? alpha : 0.0);
    } else if (a >= 27 && b >= 27) {
      int d = a - 27, e = b - 27;
      v = g54(G, d, e) - slv[d] * slv[e] * Minv + ((d == e) ? alpha : 0.0);
    } else {
      int d = (a >= 27) ? (a - 27) : (b - 27);   // la index
      int e = (a >= 27) ? b : a;                 // pr index
      v = g54(G, d, 27 + e) - slv[d] * spv[e] * Minv;
    }
    M[a * MS + b] = v;
  }
  __syncthreads();
  if (tid == 0) { piv[0] = M[0]; idiv[0] = 1.0 / M[0]; }
  __syncthreads();

  for (int k = 0; k < 53; k++) {
    double dinv = idiv[k];
    int n = 53 - k, base = k + 1;
    int ncell = n * n;
    for (int u = tid; u < ncell; u += 256) {
      int i = u / n, j = u - i * n;
      int r = base + i, c = base + j;
      double v = M[r * MS + c] - M[r * MS + k] * M[k * MS + c] * dinv;
      M[r * MS + c] = v;
      if (u == 0) { piv[base] = v; idiv[base] = 1.0 / v; }  // tid 0: next pivot
    }
    __syncthreads();
  }

  if (tid < 27) lred[tid] = log(sqrt(piv[27 + tid]) + 1e-8);
  __syncthreads();
  if (tid == 0) {
    double s = 0.0;
    for (int i = 0; i < 27; i++) s += lred[i];
    atomicAdd(out, (float)(s / 54.0));
  }
}

// ---------------------------------------------------------------------------
extern "C" void kernel_launch(void* const* d_in, const int* in_sizes, int n_in,
                              void* d_out, int out_size, void* d_ws, size_t ws_size,
                              hipStream_t stream) {
  const float* logits = (const float*)d_in[0];
  const int* labels = (const int*)d_in[1];
  float* out = (float*)d_out;

  // ws layout: Gsum fp64 (160 KB) | partials fp32 (5 MB) | shifted bf16 (10.6 MB)
  double* Gsum = (double*)d_ws;
  float* partials = (float*)((char*)d_ws + 163840);
  u16* shifted = (u16*)((char*)d_ws + 163840 + 5242880);

  hipMemsetAsync(d_out, 0, sizeof(float), stream);

  pool_kernel<<<864, 256, 0, stream>>>(logits, labels, shifted);
  gram_kernel<<<512, 256, 0, stream>>>(shifted, partials);
  reduce_kernel<<<80, 256, 0, stream>>>(partials, Gsum);
  stage2_kernel<<<NCH, 256, 0, stream>>>(Gsum, out);
}

// Round 6
// 116.488 us; speedup vs baseline: 4.2737x; 1.1720x over previous
//
#include <hip/hip_runtime.h>
#include <math.h>

// Problem constants
#define NVAL  97336           // 46^3 valid window positions
#define NCH   8               // N*C = 2*4 channels

typedef unsigned short u16;
typedef __attribute__((ext_vector_type(8))) short bf16x8;
typedef __attribute__((ext_vector_type(4))) float f32x4;
typedef __attribute__((ext_vector_type(4))) unsigned int u32x4;

// LDS staging geometry (gram kernel)
#define LINE_B 336            // 3 copies * 112 B per (x,y,vol) z-line
#define COPY_B 112            // 48 bf16 (96 B) + 16 B pad (bank spread)
#define VOL_B  21504          // 64 lines * 336
#define SHIFT_LINE_U16 144    // global pre-shifted line: 3 copies * 48 u16

// ---------------------------------------------------------------------------
// Kernel 1: fused sigmoid/one-hot + 2x2x2 max-pool -> bf16, written as 3
// z-pre-shifted copies per line: copy dz slot s holds vol[z = s+dz].
// Tail slots (s+dz>47) are zero-filled explicitly (no memset needed).
// ---------------------------------------------------------------------------
__global__ __launch_bounds__(256) void pool_kernel(
    const float* __restrict__ logits, const int* __restrict__ labels,
    u16* __restrict__ shifted) {
  int t = blockIdx.x * 256 + threadIdx.x;
  if (t >= 2 * 110592) return;
  int Z = t % 48; int tmp = t / 48;
  int Y = tmp % 48; tmp /= 48;
  int X = tmp % 48; int n = tmp / 48;
  int sb = (2 * X) * 9216 + (2 * Y) * 96 + 2 * Z;
  const int2* lb2 = (const int2*)(labels + n * 884736 + sb);
  int2 La = lb2[0], Lb = lb2[48], Lc = lb2[4608], Ld = lb2[4656];
  #pragma unroll
  for (int c = 0; c < 4; c++) {
    const float2* lg2 = (const float2*)(logits + (size_t)(n * 4 + c) * 884736 + sb);
    float2 v0 = lg2[0], v1 = lg2[48], v2 = lg2[4608], v3 = lg2[4656];
    float mx = fmaxf(fmaxf(fmaxf(v0.x, v0.y), fmaxf(v1.x, v1.y)),
                     fmaxf(fmaxf(v2.x, v2.y), fmaxf(v3.x, v3.y)));
    // max(sigmoid) == sigmoid(max); +1e-6 commutes with max
    float pr = 1.0f / (1.0f + expf(-mx)) + 1e-6f;
    int la = (La.x == c || La.y == c || Lb.x == c || Lb.y == c ||
              Lc.x == c || Lc.y == c || Ld.x == c || Ld.y == c);
    u16 la16 = la ? (u16)0x3F80 : (u16)0;         // bf16(1.0)
    unsigned int u = __float_as_uint(pr);          // round-to-nearest-even bf16
    u16 pr16 = (u16)((u + 0x7FFF + ((u >> 16) & 1)) >> 16);
    int ch = n * 4 + c;
    size_t lbase = ((size_t)(ch * 2 + 0) * 2304 + X * 48 + Y) * SHIFT_LINE_U16;
    size_t pbase = ((size_t)(ch * 2 + 1) * 2304 + X * 48 + Y) * SHIFT_LINE_U16;
    #pragma unroll
    for (int dz = 0; dz < 3; dz++) {
      int s = Z - dz;
      u16 lo = la16, po = pr16;
      if (s < 0) { s = 47 - (dz - 1 - Z); lo = 0; po = 0; }  // tail zero slots
      shifted[lbase + dz * 48 + s] = lo;
      shifted[pbase + dz * 48 + s] = po;
    }
  }
}

// ---------------------------------------------------------------------------
// Kernel 2: Gram via MFMA. W rows 0-26 = la shifts, 27-53 = pr shifts,
// 54 = ones (row sums for free), 55-63 = zero. G = (mask.W) W^T, upper
// triangle as 10 16x16 tiles. Block = (ch, 6x6 xy-tile of base positions).
// ---------------------------------------------------------------------------
#define MFMA16(A, B, C) __builtin_amdgcn_mfma_f32_16x16x32_bf16((A), (B), (C), 0, 0, 0)

#define STEP(BA, AM) do {                                                  \
    int _ba = (BA);                                                        \
    u32x4 ub0 = *(const u32x4*)(smem + _ba + laneC0);                      \
    u32x4 ub1 = *(const u32x4*)(smem + _ba + laneC1);                      \
    u32x4 ub2 = *(const u32x4*)(smem + _ba + laneC2);                      \
    u32x4 ub3 = *(const u32x4*)(smem + _ba + laneC3);                      \
    ub3 = iszero ? zer4 : (isones ? one4 : ub3);                           \
    u32x4 ua0 = ub0, ua1 = ub1, ua2 = ub2, ua3 = ub3;                      \
    ua0.w &= (AM); ua1.w &= (AM); ua2.w &= (AM); ua3.w &= (AM);            \
    bf16x8 A0 = __builtin_bit_cast(bf16x8, ua0);                           \
    bf16x8 A1 = __builtin_bit_cast(bf16x8, ua1);                           \
    bf16x8 A2 = __builtin_bit_cast(bf16x8, ua2);                           \
    bf16x8 A3 = __builtin_bit_cast(bf16x8, ua3);                           \
    bf16x8 B0 = __builtin_bit_cast(bf16x8, ub0);                           \
    bf16x8 B1 = __builtin_bit_cast(bf16x8, ub1);                           \
    bf16x8 B2 = __builtin_bit_cast(bf16x8, ub2);                           \
    bf16x8 B3 = __builtin_bit_cast(bf16x8, ub3);                           \
    acc0 = MFMA16(A0, B0, acc0);  acc1 = MFMA16(A0, B1, acc1);             \
    acc2 = MFMA16(A0, B2, acc2);  acc3 = MFMA16(A0, B3, acc3);             \
    acc4 = MFMA16(A1, B1, acc4);  acc5 = MFMA16(A1, B2, acc5);             \
    acc6 = MFMA16(A1, B3, acc6);  acc7 = MFMA16(A2, B2, acc7);             \
    acc8 = MFMA16(A2, B3, acc8);  acc9 = MFMA16(A3, B3, acc9);             \
  } while (0)

__global__ __launch_bounds__(256) void gram_kernel(
    const u16* __restrict__ shifted, float* __restrict__ partials) {
  __shared__ __align__(16) unsigned char smem[43008];
  int bx = blockIdx.x;
  int ch = bx >> 6, xt = (bx >> 3) & 7, yt = bx & 7;
  int X0 = xt * 6, Y0 = yt * 6;
  int tw = (xt == 7) ? 4 : 6, th = (yt == 7) ? 4 : 6;
  int sw = tw + 2, sh = th + 2;
  int tid = threadIdx.x;

  const u16* base = shifted + (size_t)ch * 2 * 2304 * SHIFT_LINE_U16;
  int njobs = 2 * sw * sh * 18;                  // 18 x 16B chunks per line
  for (int j = tid; j < njobs; j += 256) {
    int chunk = j % 18; int li = j / 18;
    int sy = li % sh; int t2 = li / sh; int sx = t2 % sw; int vol = t2 / sw;
    const u32x4* src = (const u32x4*)(base +
        ((size_t)vol * 2304 + (X0 + sx) * 48 + (Y0 + sy)) * SHIFT_LINE_U16);
    u32x4 v = src[chunk];
    int dz = chunk / 6, cc = chunk - dz * 6;
    *(u32x4*)(smem + vol * VOL_B + (sx * sh + sy) * LINE_B + dz * COPY_B + cc * 16) = v;
  }
  __syncthreads();

  int lane = tid & 63, w = tid >> 6;
  int q = lane >> 4, rlo = lane & 15;
#define LANEC(F) ({ int _r = (F) * 16 + rlo; int _vol = 0, _s = 0;           \
    if (_r < 27) { _s = _r; } else if (_r < 54) { _vol = 1; _s = _r - 27; }  \
    int _dx = _s / 9, _dy = (_s / 3) % 3, _dz = _s % 3;                      \
    _vol * VOL_B + (_dx * sh + _dy) * LINE_B + _dz * COPY_B; })
  int laneC0 = LANEC(0), laneC1 = LANEC(1), laneC2 = LANEC(2), laneC3 = LANEC(3);
  unsigned int am1 = (q == 1) ? 0u : ~0u;
  unsigned int am2 = (q == 3) ? 0u : ~0u;
  bool isones = (rlo == 6);    // frag3 row 54 = ones
  bool iszero = (rlo > 6);     // frag3 rows 55-63 = zero
  u32x4 one4 = {0x3F803F80u, 0x3F803F80u, 0x3F803F80u, 0x3F803F80u};
  u32x4 zer4 = {0u, 0u, 0u, 0u};

  f32x4 acc0 = {0,0,0,0}, acc1 = {0,0,0,0}, acc2 = {0,0,0,0}, acc3 = {0,0,0,0};
  f32x4 acc4 = {0,0,0,0}, acc5 = {0,0,0,0}, acc6 = {0,0,0,0}, acc7 = {0,0,0,0};
  f32x4 acc8 = {0,0,0,0}, acc9 = {0,0,0,0};

  int npl = (tw * th) >> 1;
  for (int pl = w; pl < npl; pl += 4) {
    int L0 = 2 * pl, L1 = L0 + 1;
    int lx0 = L0 / th, ly0 = L0 - lx0 * th;
    int lx1 = L1 / th, ly1 = L1 - lx1 * th;
    int U0 = (lx0 * sh + ly0) * LINE_B;
    int U1 = (lx1 * sh + ly1) * LINE_B;
    STEP(U0 + 16 * q, ~0u);
    STEP((q < 2) ? (U0 + 64 + 16 * q) : (U1 + 16 * q - 32), am1);
    STEP(U1 + 32 + 16 * q, am2);
  }
  __syncthreads();

  float* Pf = (float*)smem;
#define FL(T, A) { float* _qp = Pf + w * 2560 + (T) * 256 + lane;            \
    _qp[0] = (A).x; _qp[64] = (A).y; _qp[128] = (A).z; _qp[192] = (A).w; }
  FL(0, acc0) FL(1, acc1) FL(2, acc2) FL(3, acc3) FL(4, acc4)
  FL(5, acc5) FL(6, acc6) FL(7, acc7) FL(8, acc8) FL(9, acc9)
  __syncthreads();
  float* dst = partials + (size_t)(ch * 64 + xt * 8 + yt) * 2560;
  for (int u2 = tid; u2 < 2560; u2 += 256)
    dst[u2] = Pf[u2] + Pf[u2 + 2560] + Pf[u2 + 5120] + Pf[u2 + 7680];
}

// ---------------------------------------------------------------------------
// Kernel 3: sum 64 block-partials per channel in fp64.
// ---------------------------------------------------------------------------
__global__ __launch_bounds__(256) void reduce_kernel(
    const float* __restrict__ partials, double* __restrict__ Gsum) {
  int b = blockIdx.x; int ch = b / 10;
  int so = (b - ch * 10) * 256 + threadIdx.x;
  const float* p = partials + (size_t)ch * 64 * 2560 + so;
  double s = 0.0;
  for (int t = 0; t < 64; t++) s += (double)p[t * 2560];
  Gsum[ch * 2560 + so] = s;
}

// ---------------------------------------------------------------------------
// Kernel 4: bordered 54x54 elimination, RANK-4 BLOCKED (13 phases + tail).
// M = [[pr_cov+aI, B^T],[B, la_cov+aI]]; after eliminating pr block (27),
// trailing = appro_var+aI; pivots 27..53 = chol diag^2. M stays symmetric,
// so each thread redundantly eliminates the 4x4 pivot block in registers
// and updates its trailing cells with on-the-fly border elimination.
// ---------------------------------------------------------------------------
#define MS 55   // row stride (doubles)
__device__ inline double g54(const double* __restrict__ G, int R, int C) {
  int I = R >> 4, J = C >> 4;
  if (I > J) { int tt = R; R = C; C = tt; I = R >> 4; J = C >> 4; }
  int tile = 4 * I - ((I * (I - 1)) >> 1) + (J - I);
  int r = R & 15, c = C & 15;
  return G[tile * 256 + (r & 3) * 64 + ((r >> 2) << 4) + c];
}

__global__ __launch_bounds__(256) void stage2_kernel(
    const double* __restrict__ Gsum, float* __restrict__ out) {
  __shared__ double M[54 * MS];
  __shared__ double slv[27], spv[27], piv[54], lred[27];
  int ch = blockIdx.x, tid = threadIdx.x;
  const double Minv = 1.0 / (double)NVAL;
  const double alpha = 5e-4;
  const double* G = Gsum + ch * 2560;

  if (tid < 27) { slv[tid] = g54(G, tid, 54); spv[tid] = g54(G, 27 + tid, 54); }
  __syncthreads();
  // Build bordered matrix: indices 0..26 = pr dims, 27..53 = la dims
  for (int u = tid; u < 54 * 54; u += 256) {
    int a = u / 54, b = u - a * 54;
    double v;
    if (a < 27 && b < 27) {
      v = g54(G, 27 + a, 27 + b) - spv[a] * spv[b] * Minv + ((a == b) ? alpha : 0.0);
    } else if (a >= 27 && b >= 27) {
      int d = a - 27, e = b - 27;
      v = g54(G, d, e) - slv[d] * slv[e] * Minv + ((d == e) ? alpha : 0.0);
    } else {
      int d = (a >= 27) ? (a - 27) : (b - 27);   // la index
      int e = (a >= 27) ? b : a;                 // pr index
      v = g54(G, d, 27 + e) - slv[d] * spv[e] * Minv;
    }
    M[a * MS + b] = v;
  }
  __syncthreads();

  // 13 rank-4 phases (pivots 0..51)
  for (int p = 0; p < 13; p++) {
    int k0 = p * 4;
    // Pivot block (broadcast LDS reads), eliminated locally by every thread
    double P00 = M[(k0+0)*MS + k0+0], P01 = M[(k0+0)*MS + k0+1],
           P02 = M[(k0+0)*MS + k0+2], P03 = M[(k0+0)*MS + k0+3];
    double P11 = M[(k0+1)*MS + k0+1], P12 = M[(k0+1)*MS + k0+2],
           P13 = M[(k0+1)*MS + k0+3];
    double P22 = M[(k0+2)*MS + k0+2], P23 = M[(k0+2)*MS + k0+3];
    double P33 = M[(k0+3)*MS + k0+3];
    // symmetric lower entries
    double P10 = M[(k0+1)*MS + k0+0], P20 = M[(k0+2)*MS + k0+0],
           P21 = M[(k0+2)*MS + k0+1], P30 = M[(k0+3)*MS + k0+0],
           P31 = M[(k0+3)*MS + k0+1], P32 = M[(k0+3)*MS + k0+2];
    double id0 = 1.0 / P00;
    { double l = P10 * id0; P11 -= l * P01; P12 -= l * P02; P13 -= l * P03; }
    { double l = P20 * id0; P21 -= l * P01; P22 -= l * P02; P23 -= l * P03; }
    { double l = P30 * id0; P31 -= l * P01; P32 -= l * P02; P33 -= l * P03; }
    double id1 = 1.0 / P11;
    { double l = P21 * id1; P22 -= l * P12; P23 -= l * P13; }
    { double l = P31 * id1; P32 -= l * P12; P33 -= l * P13; }
    double id2 = 1.0 / P22;
    { double l = P32 * id2; P33 -= l * P23; }
    double id3 = 1.0 / P33;
    if (tid == 0) {
      piv[k0] = P00; piv[k0+1] = P11; piv[k0+2] = P22; piv[k0+3] = P33;
    }
    int base = k0 + 4, n = 54 - base;
    int ncell = n * n;
    for (int u = tid; u < ncell; u += 256) {
      int i = base + u / n, j = base + u % n;
      const double* Ri = M + i * MS + k0;
      const double* Rj = M + j * MS + k0;
      double a0 = Ri[0], a1 = Ri[1], a2 = Ri[2], a3 = Ri[3];
      double b0 = Rj[0], b1 = Rj[1], b2 = Rj[2], b3 = Rj[3];
      double da0 = a0 * id0;
      a1 -= da0 * P01;                    double da1 = a1 * id1;
      a2 -= da0 * P02 + da1 * P12;        double da2 = a2 * id2;
      a3 -= da0 * P03 + da1 * P13 + da2 * P23;  double da3 = a3 * id3;
      double db0 = b0 * id0;
      b1 -= db0 * P01;
      b2 -= db0 * P02 + (b1 * id1) * P12;
      b3 -= db0 * P03 + (b1 * id1) * P13 + (b2 * id2) * P23;
      M[i * MS + j] -= da0 * b0 + da1 * b1 + da2 * b2 + da3 * b3;
    }
    __syncthreads();
  }
  // Tail: pivots 52, 53 in closed form from the 2x2 trailing block
  if (tid == 0) {
    double m00 = M[52 * MS + 52], m01 = M[52 * MS + 53], m10 = M[53 * MS + 52];
    double m11 = M[53 * MS + 53];
    piv[52] = m00;
    piv[53] = m11 - m10 * m01 / m00;
  }
  __syncthreads();

  if (tid < 27) lred[tid] = log(sqrt(piv[27 + tid]) + 1e-8);
  __syncthreads();
  if (tid == 0) {
    double s = 0.0;
    for (int i = 0; i < 27; i++) s += lred[i];
    atomicAdd(out, (float)(s / 54.0));
  }
}

// ---------------------------------------------------------------------------
extern "C" void kernel_launch(void* const* d_in, const int* in_sizes, int n_in,
                              void* d_out, int out_size, void* d_ws, size_t ws_size,
                              hipStream_t stream) {
  const float* logits = (const float*)d_in[0];
  const int* labels = (const int*)d_in[1];
  float* out = (float*)d_out;

  // ws layout: Gsum fp64 (160 KB) | partials fp32 (5 MB) | shifted bf16 (10.6 MB)
  double* Gsum = (double*)d_ws;
  float* partials = (float*)((char*)d_ws + 163840);
  u16* shifted = (u16*)((char*)d_ws + 163840 + 5242880);

  hipMemsetAsync(d_out, 0, sizeof(float), stream);

  pool_kernel<<<864, 256, 0, stream>>>(logits, labels, shifted);
  gram_kernel<<<512, 256, 0, stream>>>(shifted, partials);
  reduce_kernel<<<80, 256, 0, stream>>>(partials, Gsum);
  stage2_kernel<<<NCH, 256, 0, stream>>>(Gsum, out);
}

// Round 7
// 108.835 us; speedup vs baseline: 4.5743x; 1.0703x over previous
//
#include <hip/hip_runtime.h>
#include <math.h>

// Problem constants
#define NVAL  97336           // 46^3 valid window positions
#define NCH   8               // N*C = 2*4 channels

typedef unsigned short u16;
typedef __attribute__((ext_vector_type(8))) short bf16x8;
typedef __attribute__((ext_vector_type(4))) float f32x4;
typedef __attribute__((ext_vector_type(4))) unsigned int u32x4;

// LDS staging geometry (gram kernel)
#define LINE_B 336            // 3 copies * 112 B per (x,y,vol) z-line
#define COPY_B 112            // 48 bf16 (96 B) + 16 B pad (bank spread)
#define VOL_B  21504          // 64 lines * 336
#define SHIFT_LINE_U16 144    // global pre-shifted line: 3 copies * 48 u16

// ---------------------------------------------------------------------------
// Kernel 1: fused sigmoid/one-hot + 2x2x2 max-pool -> bf16, written as 3
// z-pre-shifted copies per line: copy dz slot s holds vol[z = s+dz].
// Tail slots (s+dz>47) are zero-filled explicitly (no memset needed).
// ---------------------------------------------------------------------------
__global__ __launch_bounds__(256) void pool_kernel(
    const float* __restrict__ logits, const int* __restrict__ labels,
    u16* __restrict__ shifted) {
  int t = blockIdx.x * 256 + threadIdx.x;
  if (t >= 2 * 110592) return;
  int Z = t % 48; int tmp = t / 48;
  int Y = tmp % 48; tmp /= 48;
  int X = tmp % 48; int n = tmp / 48;
  int sb = (2 * X) * 9216 + (2 * Y) * 96 + 2 * Z;
  const int2* lb2 = (const int2*)(labels + n * 884736 + sb);
  int2 La = lb2[0], Lb = lb2[48], Lc = lb2[4608], Ld = lb2[4656];
  #pragma unroll
  for (int c = 0; c < 4; c++) {
    const float2* lg2 = (const float2*)(logits + (size_t)(n * 4 + c) * 884736 + sb);
    float2 v0 = lg2[0], v1 = lg2[48], v2 = lg2[4608], v3 = lg2[4656];
    float mx = fmaxf(fmaxf(fmaxf(v0.x, v0.y), fmaxf(v1.x, v1.y)),
                     fmaxf(fmaxf(v2.x, v2.y), fmaxf(v3.x, v3.y)));
    // max(sigmoid) == sigmoid(max); +1e-6 commutes with max
    float pr = 1.0f / (1.0f + expf(-mx)) + 1e-6f;
    int la = (La.x == c || La.y == c || Lb.x == c || Lb.y == c ||
              Lc.x == c || Lc.y == c || Ld.x == c || Ld.y == c);
    u16 la16 = la ? (u16)0x3F80 : (u16)0;         // bf16(1.0)
    unsigned int u = __float_as_uint(pr);          // round-to-nearest-even bf16
    u16 pr16 = (u16)((u + 0x7FFF + ((u >> 16) & 1)) >> 16);
    int ch = n * 4 + c;
    size_t lbase = ((size_t)(ch * 2 + 0) * 2304 + X * 48 + Y) * SHIFT_LINE_U16;
    size_t pbase = ((size_t)(ch * 2 + 1) * 2304 + X * 48 + Y) * SHIFT_LINE_U16;
    #pragma unroll
    for (int dz = 0; dz < 3; dz++) {
      int s = Z - dz;
      u16 lo = la16, po = pr16;
      if (s < 0) { s = 47 - (dz - 1 - Z); lo = 0; po = 0; }  // tail zero slots
      shifted[lbase + dz * 48 + s] = lo;
      shifted[pbase + dz * 48 + s] = po;
    }
  }
}

// ---------------------------------------------------------------------------
// Kernel 2: Gram via MFMA. W rows 0-26 = la shifts, 27-53 = pr shifts,
// 54 = ones (row sums for free), 55-63 = zero. G = (mask.W) W^T, upper
// triangle as 10 16x16 tiles. Block = (ch, 6x6 xy-tile of base positions).
// Staging is a fixed 8x8 line grid (clamped at volume edge; clamped lines
// are garbage but provably never read by valid tasks).
// ---------------------------------------------------------------------------
#define MFMA16(A, B, C) __builtin_amdgcn_mfma_f32_16x16x32_bf16((A), (B), (C), 0, 0, 0)

#define STEP(BA, AM) do {                                                  \
    int _ba = (BA);                                                        \
    u32x4 ub0 = *(const u32x4*)(smem + _ba + laneC0);                      \
    u32x4 ub1 = *(const u32x4*)(smem + _ba + laneC1);                      \
    u32x4 ub2 = *(const u32x4*)(smem + _ba + laneC2);                      \
    u32x4 ub3 = *(const u32x4*)(smem + _ba + laneC3);                      \
    ub3 = iszero ? zer4 : (isones ? one4 : ub3);                           \
    u32x4 ua0 = ub0, ua1 = ub1, ua2 = ub2, ua3 = ub3;                      \
    ua0.w &= (AM); ua1.w &= (AM); ua2.w &= (AM); ua3.w &= (AM);            \
    bf16x8 A0 = __builtin_bit_cast(bf16x8, ua0);                           \
    bf16x8 A1 = __builtin_bit_cast(bf16x8, ua1);                           \
    bf16x8 A2 = __builtin_bit_cast(bf16x8, ua2);                           \
    bf16x8 A3 = __builtin_bit_cast(bf16x8, ua3);                           \
    bf16x8 B0 = __builtin_bit_cast(bf16x8, ub0);                           \
    bf16x8 B1 = __builtin_bit_cast(bf16x8, ub1);                           \
    bf16x8 B2 = __builtin_bit_cast(bf16x8, ub2);                           \
    bf16x8 B3 = __builtin_bit_cast(bf16x8, ub3);                           \
    acc0 = MFMA16(A0, B0, acc0);  acc1 = MFMA16(A0, B1, acc1);             \
    acc2 = MFMA16(A0, B2, acc2);  acc3 = MFMA16(A0, B3, acc3);             \
    acc4 = MFMA16(A1, B1, acc4);  acc5 = MFMA16(A1, B2, acc5);             \
    acc6 = MFMA16(A1, B3, acc6);  acc7 = MFMA16(A2, B2, acc7);             \
    acc8 = MFMA16(A2, B3, acc8);  acc9 = MFMA16(A3, B3, acc9);             \
  } while (0)

__global__ __launch_bounds__(256) void gram_kernel(
    const u16* __restrict__ shifted, float* __restrict__ partials) {
  __shared__ __align__(16) unsigned char smem[43008];
  int bx = blockIdx.x;
  int ch = bx >> 6, xt = (bx >> 3) & 7, yt = bx & 7;
  int X0 = xt * 6, Y0 = yt * 6;
  int tw = (xt == 7) ? 4 : 6, th = (yt == 7) ? 4 : 6;
  int tid = threadIdx.x;

  // Stage fixed 8x8 lines x 2 vols, 3 pre-shifted copies each, into LDS
  const u16* base = shifted + (size_t)ch * 2 * 2304 * SHIFT_LINE_U16;
  for (int j = tid; j < 2304; j += 256) {        // 2*64*18 chunks, 9 iters
    int chunk = j % 18; int li = j / 18;         // li 0..127
    int sy = li & 7, sx = (li >> 3) & 7, vol = li >> 6;
    int gx = X0 + sx; if (gx > 47) gx = 47;      // clamp: garbage, never read
    int gy = Y0 + sy; if (gy > 47) gy = 47;
    const u32x4* src = (const u32x4*)(base +
        ((size_t)vol * 2304 + gx * 48 + gy) * SHIFT_LINE_U16);
    u32x4 v = src[chunk];
    int dz = chunk / 6, cc = chunk - dz * 6;
    *(u32x4*)(smem + vol * VOL_B + ((sx << 3) + sy) * LINE_B + dz * COPY_B + cc * 16) = v;
  }
  __syncthreads();

  int lane = tid & 63, w = tid >> 6;
  int q = lane >> 4, rlo = lane & 15;
#define LANEC(F) ({ int _r = (F) * 16 + rlo; int _vol = 0, _s = 0;           \
    if (_r < 27) { _s = _r; } else if (_r < 54) { _vol = 1; _s = _r - 27; }  \
    int _dx = _s / 9, _dy = (_s / 3) % 3, _dz = _s % 3;                      \
    _vol * VOL_B + ((_dx << 3) + _dy) * LINE_B + _dz * COPY_B; })
  int laneC0 = LANEC(0), laneC1 = LANEC(1), laneC2 = LANEC(2), laneC3 = LANEC(3);
  unsigned int am1 = (q == 1) ? 0u : ~0u;
  unsigned int am2 = (q == 3) ? 0u : ~0u;
  bool isones = (rlo == 6);    // frag3 row 54 = ones
  bool iszero = (rlo > 6);     // frag3 rows 55-63 = zero
  u32x4 one4 = {0x3F803F80u, 0x3F803F80u, 0x3F803F80u, 0x3F803F80u};
  u32x4 zer4 = {0u, 0u, 0u, 0u};

  f32x4 acc0 = {0,0,0,0}, acc1 = {0,0,0,0}, acc2 = {0,0,0,0}, acc3 = {0,0,0,0};
  f32x4 acc4 = {0,0,0,0}, acc5 = {0,0,0,0}, acc6 = {0,0,0,0}, acc7 = {0,0,0,0};
  f32x4 acc8 = {0,0,0,0}, acc9 = {0,0,0,0};

  int npl = (tw * th) >> 1;
  for (int pl = w; pl < npl; pl += 4) {
    int L0 = 2 * pl, L1 = L0 + 1;
    int lx0 = L0 / th, ly0 = L0 - lx0 * th;
    int lx1 = L1 / th, ly1 = L1 - lx1 * th;
    int U0 = ((lx0 << 3) + ly0) * LINE_B;
    int U1 = ((lx1 << 3) + ly1) * LINE_B;
    STEP(U0 + 16 * q, ~0u);
    STEP((q < 2) ? (U0 + 64 + 16 * q) : (U1 + 16 * q - 32), am1);
    STEP(U1 + 32 + 16 * q, am2);
  }
  __syncthreads();

  float* Pf = (float*)smem;
#define FL(T, A) { float* _qp = Pf + w * 2560 + (T) * 256 + lane;            \
    _qp[0] = (A).x; _qp[64] = (A).y; _qp[128] = (A).z; _qp[192] = (A).w; }
  FL(0, acc0) FL(1, acc1) FL(2, acc2) FL(3, acc3) FL(4, acc4)
  FL(5, acc5) FL(6, acc6) FL(7, acc7) FL(8, acc8) FL(9, acc9)
  __syncthreads();
  float* dst = partials + (size_t)(ch * 64 + xt * 8 + yt) * 2560;
  for (int u2 = tid; u2 < 2560; u2 += 256)
    dst[u2] = Pf[u2] + Pf[u2 + 2560] + Pf[u2 + 5120] + Pf[u2 + 7680];
}

// ---------------------------------------------------------------------------
// Kernel 3: sum 64 block-partials per channel in fp64; block 0 zeroes out.
// ---------------------------------------------------------------------------
__global__ __launch_bounds__(256) void reduce_kernel(
    const float* __restrict__ partials, double* __restrict__ Gsum,
    float* __restrict__ out) {
  int b = blockIdx.x; int ch = b / 10;
  if (b == 0 && threadIdx.x == 0) out[0] = 0.0f;
  int so = (b - ch * 10) * 256 + threadIdx.x;
  const float* p = partials + (size_t)ch * 64 * 2560 + so;
  double s = 0.0;
  for (int t = 0; t < 64; t++) s += (double)p[t * 2560];
  Gsum[ch * 2560 + so] = s;
}

// ---------------------------------------------------------------------------
// Kernel 4: bordered 54x54 elimination, RANK-8 BLOCKED (6 phases + 6x6 tail).
// M = [[pr_cov+aI, B^T],[B, la_cov+aI]]; pivots 27..53 = chol(appro+aI)^2.
// Lower triangle only (symmetric). Each thread redundantly LDL^T-factors the
// 8x8 pivot block in registers; cell (i,j) update = a.Binv.b via two forward
// solves through unit-lower L and a d^-1-weighted dot.
// ---------------------------------------------------------------------------
#define MS 55   // row stride (doubles)
__device__ inline double g54(const double* __restrict__ G, int R, int C) {
  int I = R >> 4, J = C >> 4;
  if (I > J) { int tt = R; R = C; C = tt; I = R >> 4; J = C >> 4; }
  int tile = 4 * I - ((I * (I - 1)) >> 1) + (J - I);
  int r = R & 15, c = C & 15;
  return G[tile * 256 + (r & 3) * 64 + ((r >> 2) << 4) + c];
}

__device__ inline int tri_row(int u) {
  int a = (int)((sqrtf(8.0f * (float)u + 1.0f) - 1.0f) * 0.5f);
  while ((a + 1) * (a + 2) / 2 <= u) a++;
  while (a * (a + 1) / 2 > u) a--;
  return a;
}

__global__ __launch_bounds__(256) void stage2_kernel(
    const double* __restrict__ Gsum, float* __restrict__ out) {
  __shared__ double M[54 * MS];
  __shared__ double slv[27], spv[27], piv[54], lred[27];
  int ch = blockIdx.x, tid = threadIdx.x;
  const double Minv = 1.0 / (double)NVAL;
  const double alpha = 5e-4;
  const double* G = Gsum + ch * 2560;

  if (tid < 27) { slv[tid] = g54(G, tid, 54); spv[tid] = g54(G, 27 + tid, 54); }
  __syncthreads();
  // Build lower triangle of bordered matrix: 0..26 = pr dims, 27..53 = la
  for (int u = tid; u < 1485; u += 256) {
    int a = tri_row(u);
    int b = u - a * (a + 1) / 2;               // b <= a
    double v;
    if (a < 27) {                               // pr-pr
      v = g54(G, 27 + a, 27 + b) - spv[a] * spv[b] * Minv + ((a == b) ? alpha : 0.0);
    } else if (b >= 27) {                       // la-la
      int d = a - 27, e = b - 27;
      v = g54(G, d, e) - slv[d] * slv[e] * Minv + ((d == e) ? alpha : 0.0);
    } else {                                    // la row, pr col
      v = g54(G, a - 27, 27 + b) - slv[a - 27] * spv[b] * Minv;
    }
    M[a * MS + b] = v;
  }
  __syncthreads();

  #pragma unroll 1
  for (int phase = 0; phase < 6; phase++) {
    int k0 = phase * 8;
    // Load lower 8x8 pivot block (broadcast reads), factor LDL^T in regs
    double P[8][8];
    #pragma unroll
    for (int k = 0; k < 8; k++)
      #pragma unroll
      for (int j = 0; j <= k; j++)
        P[k][j] = M[(k0 + k) * MS + (k0 + j)];
    double idv[8];
    #pragma unroll
    for (int k = 0; k < 8; k++) {
      idv[k] = 1.0 / P[k][k];
      // trailing update with raw column entries, then scale to multipliers
      #pragma unroll
      for (int i = k + 1; i < 8; i++) {
        double l = P[i][k] * idv[k];
        #pragma unroll
        for (int j = k + 1; j <= i; j++)
          P[i][j] -= l * P[j][k];
      }
      #pragma unroll
      for (int i = k + 1; i < 8; i++) P[i][k] *= idv[k];
    }
    if (tid == 0) {
      #pragma unroll
      for (int k = 0; k < 8; k++) piv[k0 + k] = P[k][k];
    }
    int base = k0 + 8, n = 54 - base;
    int ncell = n * (n + 1) / 2;
    for (int u = tid; u < ncell; u += 256) {
      int ii = tri_row(u);
      int jj = u - ii * (ii + 1) / 2;
      int i = base + ii, j = base + jj;
      double av[8], bv[8];
      #pragma unroll
      for (int k = 0; k < 8; k++) av[k] = M[i * MS + k0 + k];
      #pragma unroll
      for (int k = 0; k < 8; k++) bv[k] = M[j * MS + k0 + k];
      #pragma unroll
      for (int k = 1; k < 8; k++) {
        #pragma unroll
        for (int m = 0; m < k; m++) {
          av[k] -= P[k][m] * av[m];
          bv[k] -= P[k][m] * bv[m];
        }
      }
      double acc = 0.0;
      #pragma unroll
      for (int k = 0; k < 8; k++) acc += av[k] * (bv[k] * idv[k]);
      M[i * MS + j] -= acc;
    }
    __syncthreads();
  }

  // Tail: 6x6 trailing block, pivots 48..53
  if (tid == 0) {
    double T[6][6];
    #pragma unroll
    for (int k = 0; k < 6; k++)
      #pragma unroll
      for (int j = 0; j <= k; j++)
        T[k][j] = M[(48 + k) * MS + (48 + j)];
    #pragma unroll
    for (int k = 0; k < 6; k++) {
      double dk = T[k][k];
      piv[48 + k] = dk;
      double id = 1.0 / dk;
      #pragma unroll
      for (int i = k + 1; i < 6; i++) {
        double l = T[i][k] * id;
        #pragma unroll
        for (int j = k + 1; j <= i; j++)
          T[i][j] -= l * T[j][k];
      }
    }
  }
  __syncthreads();

  if (tid < 27) lred[tid] = log(sqrt(piv[27 + tid]) + 1e-8);
  __syncthreads();
  if (tid == 0) {
    double s = 0.0;
    for (int i = 0; i < 27; i++) s += lred[i];
    atomicAdd(out, (float)(s / 54.0));
  }
}

// ---------------------------------------------------------------------------
extern "C" void kernel_launch(void* const* d_in, const int* in_sizes, int n_in,
                              void* d_out, int out_size, void* d_ws, size_t ws_size,
                              hipStream_t stream) {
  const float* logits = (const float*)d_in[0];
  const int* labels = (const int*)d_in[1];
  float* out = (float*)d_out;

  // ws layout: Gsum fp64 (160 KB) | partials fp32 (5 MB) | shifted bf16 (10.6 MB)
  double* Gsum = (double*)d_ws;
  float* partials = (float*)((char*)d_ws + 163840);
  u16* shifted = (u16*)((char*)d_ws + 163840 + 5242880);

  pool_kernel<<<864, 256, 0, stream>>>(logits, labels, shifted);
  gram_kernel<<<512, 256, 0, stream>>>(shifted, partials);
  reduce_kernel<<<80, 256, 0, stream>>>(partials, Gsum, out);
  stage2_kernel<<<NCH, 256, 0, stream>>>(Gsum, out);
}